// Round 6
// baseline (8188.955 us; speedup 1.0000x reference)
//
#include <hip/hip_runtime.h>

// ---------------------------------------------------------------------------
// VehicleTrajectoryDecoder: B=32, N=256, D=512, H=8 (dh=64), T=60, DFF=2048.
// R6: R5 counters (VALUBusy 8%, phases ~14us vs ~2us work) show the grid
// barrier still costs ~12us: 255 blocks spin-load ONE release word -> MALL
// line hotspot (read-side twin of R3's atomic-counter bug). Fix: per-block
// padded release slots; block 0's 256 threads store all slots in parallel
// (one instruction, independent lines); each waiter polls only its own line.
// No shared line remains in the barrier. Everything else unchanged from R5.
// ---------------------------------------------------------------------------

#define NB 32
#define NN 256
#define DD 512
#define NH 8
#define DH 64
#define TT 60
#define DF 2048
#define NBLK 256
#define FLAG_STRIDE 32   // 128B per flag line

typedef unsigned short ushort_t;

// ---- workspace layout (float element offsets) ------------------------------
constexpr size_t SZ_KV  = (size_t)NB * NN * DD;     // 4194304
constexpr size_t SZ_SA  = (size_t)NB * TT * DD;     // 983040
constexpr size_t SZ_ROW = (size_t)NB * DD;          // 16384
// precompute-only fp32 scratch (dead before decode starts):
constexpr size_t OFF_KS32 = 0;
constexpr size_t OFF_VS32 = SZ_KV;
constexpr size_t OFF_KC32 = 2 * SZ_KV;
constexpr size_t OFF_VC32 = 3 * SZ_KV;
// decode-time overlay of the scratch region:
constexpr size_t OFF_KSA = 0;                 // fp32 [b][t][d]
constexpr size_t OFF_VSA = SZ_SA;
constexpr size_t OFF_ACT = 2 * SZ_SA;
constexpr size_t OFF_X   = OFF_ACT;
constexpr size_t OFF_QSA = OFF_X   + SZ_ROW;
constexpr size_t OFF_QS  = OFF_QSA + SZ_ROW;
constexpr size_t OFF_ASA = OFF_QS  + SZ_ROW;
constexpr size_t OFF_ASP = OFF_ASA + SZ_ROW;
constexpr size_t OFF_ACA = OFF_ASP + SZ_ROW;
constexpr size_t OFF_U1  = OFF_ACA + SZ_ROW;
constexpr size_t OFF_Y1  = OFF_U1  + SZ_ROW;
constexpr size_t OFF_QC  = OFF_Y1  + SZ_ROW;
constexpr size_t OFF_U2  = OFF_QC  + SZ_ROW;
constexpr size_t OFF_CTX = OFF_U2  + SZ_ROW;
constexpr size_t OFF_U3  = OFF_CTX + SZ_ROW;
constexpr size_t OFF_H   = OFF_U3  + SZ_ROW;  // hbuf [32][2048]
// bf16 K/V (ushort) base, after the 64MB scratch:
constexpr size_t OFF_BF  = 4 * SZ_KV;         // floats; cast to ushort*
constexpr size_t UOFF_KST = 0;                // KsT bf16 [b][d][n]
constexpr size_t UOFF_KCT = SZ_KV;            // KcT bf16 [b][d][n]
constexpr size_t UOFF_VS  = 2 * SZ_KV;        // Vs  bf16 [b][n][d]
constexpr size_t UOFF_VC  = 3 * SZ_KV;        // Vc  bf16 [b][n][d]
constexpr size_t OFF_WT  = OFF_BF + 2 * SZ_KV;        // 8 transposed 512x512 fp32
constexpr size_t OFF_W1T = OFF_WT  + 8ull * DD * DD;  // [512][2048]
constexpr size_t OFF_W2T = OFF_W1T + (size_t)DD * DF; // [2048][512]
constexpr size_t OFF_FLG = OFF_W2T + (size_t)DF * DD; // arrival flags + release slots
// flags: u32[256*32]; rels: u32[256*32] right after. 64KB total.

// ---- sc1 (agent-scope, MALL-coherent) access helpers ------------------------
__device__ __forceinline__ float ldg_a(const float* p) {
  return __hip_atomic_load(p, __ATOMIC_RELAXED, __HIP_MEMORY_SCOPE_AGENT);
}
__device__ __forceinline__ void stg_a(float* p, float v) {
  __hip_atomic_store(p, v, __ATOMIC_RELAXED, __HIP_MEMORY_SCOPE_AGENT);
}
__device__ __forceinline__ float bf2f(ushort_t u) {
  return __uint_as_float(((unsigned)u) << 16);
}
__device__ __forceinline__ ushort_t f2bf(float f) {
  unsigned u = __float_as_uint(f);
  return (ushort_t)((u + 0x7FFFu + ((u >> 16) & 1u)) >> 16);
}

// ---- params ----------------------------------------------------------------
struct Params {
  const float *pe;
  const float *sa_bq, *sa_bk, *sa_bv, *sa_bo;
  const float *s_bq, *s_bo, *ca_bq, *ca_bo;
  const float *ln1w, *ln1b, *ln2w, *ln2b, *ln3w, *ln3b;
  const float *b1, *b2, *Wout, *bout;
  const float *wt8, *W1t, *W2t;
  const ushort_t *KsTb, *KcTb, *VsB, *VcB;
  float *Ksa, *Vsa, *xcur, *qsa, *qs, *aSA, *aSP, *aCA;
  float *u1, *y1, *qc, *u2, *ctx, *u3, *hbuf;
  float *out;
  unsigned *flags;   // arrival flags, 128B stride
  unsigned *rels;    // per-block release slots, 128B stride
};

// ---- grid barrier: fully distributed, no shared lines -----------------------
__device__ __forceinline__ void gsync(unsigned* flags, unsigned* rels,
                                      unsigned& round, int tid, int bid) {
  __builtin_amdgcn_s_waitcnt(0);   // drain this wave's vmem (sc1 data stores)
  __syncthreads();
  round++;
  if (bid == 0) {
    if (tid > 0 && tid < NBLK) {   // thread i polls block i's arrival line
      while (__hip_atomic_load(&flags[(size_t)tid * FLAG_STRIDE],
                               __ATOMIC_RELAXED, __HIP_MEMORY_SCOPE_AGENT) < round)
        __builtin_amdgcn_s_sleep(1);
    }
    __syncthreads();
    // 256 parallel stores to 256 independent release lines (one instruction)
    __hip_atomic_store(&rels[(size_t)tid * FLAG_STRIDE], round,
                       __ATOMIC_RELAXED, __HIP_MEMORY_SCOPE_AGENT);
  } else {
    if (tid == 0) {
      __hip_atomic_store(&flags[(size_t)bid * FLAG_STRIDE], round,
                         __ATOMIC_RELAXED, __HIP_MEMORY_SCOPE_AGENT);
      while (__hip_atomic_load(&rels[(size_t)bid * FLAG_STRIDE],
                               __ATOMIC_RELAXED, __HIP_MEMORY_SCOPE_AGENT) < round)
        __builtin_amdgcn_s_sleep(1);
    }
  }
  __syncthreads();
}

// stage 4 rows of 512 floats from a mutable buffer (sc1 scalar loads)
__device__ __forceinline__ void stage4a(float* sX, const float* src, int tid) {
  #pragma unroll
  for (int q = 0; q < 8; q++) sX[q * 256 + tid] = ldg_a(src + q * 256 + tid);
}

// in-place LayerNorm of 4 LDS rows (wave w handles row w)
__device__ __forceinline__ void ln4(float* sX, const float* w, const float* b,
                                    float* lm, float* li, int tid) {
  int wv = tid >> 6, lane = tid & 63;
  float s = 0.f, q = 0.f;
  #pragma unroll
  for (int i = 0; i < 8; i++) {
    float v = sX[wv * DD + lane + i * 64];
    s += v; q += v * v;
  }
  #pragma unroll
  for (int m = 32; m >= 1; m >>= 1) { s += __shfl_xor(s, m); q += __shfl_xor(q, m); }
  if (lane == 0) {
    float mm = s * (1.0f / 512.0f);
    lm[wv] = mm;
    li[wv] = rsqrtf(q * (1.0f / 512.0f) - mm * mm + 1e-5f);
  }
  __syncthreads();
  float w0 = w[tid], w1 = w[tid + 256], b0 = b[tid], b1 = b[tid + 256];
  #pragma unroll
  for (int r = 0; r < 4; r++) {
    sX[r * DD + tid]       = (sX[r * DD + tid]       - lm[r]) * li[r] * w0 + b0;
    sX[r * DD + tid + 256] = (sX[r * DD + tid + 256] - lm[r]) * li[r] * w1 + b1;
  }
  __syncthreads();
}

// GEMV: 1 output/thread; 4 rows in sX; weight column-major [k][col] cached
__device__ __forceinline__ float gemv1(const float* sX, const float* wp,
                                       int ldw, int tid) {
  const float* xr = sX + (tid >> 6) * DD;
  float acc = 0.f;
  for (int k = 0; k < DD; k += 4) {
    float w0 = wp[(size_t)(k + 0) * ldw];
    float w1 = wp[(size_t)(k + 1) * ldw];
    float w2 = wp[(size_t)(k + 2) * ldw];
    float w3 = wp[(size_t)(k + 3) * ldw];
    float4 xv = *(const float4*)(xr + k);
    acc += xv.x * w0 + xv.y * w1 + xv.z * w2 + xv.w * w3;
  }
  return acc;
}

// attention over 256 keys for one (b,h), bf16 KT [d][n] / V [n][512]
__device__ __forceinline__ void attn256_bf16(
    const float* __restrict__ qbuf, int b, int h,
    const ushort_t* __restrict__ KTb, const ushort_t* __restrict__ Vb,
    float* __restrict__ outrow,
    float* sQh, float* sP, float* sB, float* redM, float* redS, int tid) {
  int w = tid >> 6, lane = tid & 63;
  if (tid < DH) sQh[tid] = ldg_a(qbuf + (size_t)b * DD + h * DH + tid);
  __syncthreads();
  const ushort_t* kp = KTb + (size_t)b * DD * NN + (size_t)(h * DH) * NN + tid;
  float a = 0.f;
  #pragma unroll 8
  for (int i = 0; i < DH; i++) a += sQh[i] * bf2f(kp[(size_t)i * NN]);
  a *= 0.125f;
  float m = a;
  #pragma unroll
  for (int s = 32; s >= 1; s >>= 1) m = fmaxf(m, __shfl_xor(m, s));
  if (lane == 0) redM[w] = m;
  __syncthreads();
  m = fmaxf(fmaxf(redM[0], redM[1]), fmaxf(redM[2], redM[3]));
  float e = __expf(a - m);
  float ss = e;
  #pragma unroll
  for (int s = 32; s >= 1; s >>= 1) ss += __shfl_xor(ss, s);
  if (lane == 0) redS[w] = ss;
  sP[tid] = e;
  __syncthreads();
  float inv = 1.f / (redS[0] + redS[1] + redS[2] + redS[3]);
  int g = tid >> 6, d = tid & 63;
  const ushort_t* vp = Vb + (size_t)b * NN * DD + (size_t)(g * 64) * DD + h * DH + d;
  float acc = 0.f;
  #pragma unroll 4
  for (int n = 0; n < 64; n++) acc += sP[g * 64 + n] * bf2f(vp[(size_t)n * DD]);
  sB[tid] = acc;
  __syncthreads();
  if (tid < 64)
    stg_a(outrow + h * DH + tid,
          (sB[tid] + sB[64 + tid] + sB[128 + tid] + sB[192 + tid]) * inv);
  __syncthreads();
}

// ---- persistent decode ------------------------------------------------------
__global__ __launch_bounds__(256) void decode_persistent(Params P) {
  __shared__ __align__(16) float sX[4 * DD];
  __shared__ float sAux[128];
  int tid = threadIdx.x;
  int bid = blockIdx.x;
  unsigned round = 0;

  float* lm   = sAux;
  float* li   = sAux + 8;
  float* red  = sAux + 16;   // 24
  float* redM = sAux + 16;
  float* redS = sAux + 24;
  float* sInv = sAux + 40;
  float* sQh  = sAux + 48;   // 64

  for (int t = 0; t < TT; t++) {
    // ---- Phase A: proj4. cs=bid&31, bg=bid>>5 ------------------------------
    {
      int cs = bid & 31, bg = bid >> 5;
      int m = cs >> 3, jb = cs & 7;
      stage4a(sX, P.xcur + (size_t)(bg * 4) * DD, tid);
      __syncthreads();
      int col = jb * 64 + (tid & 63);
      int b = bg * 4 + (tid >> 6);
      const float* wp = P.wt8 + (size_t)m * DD * DD + col;  // 0:saWq 1:saWk 2:saWv 3:sWq
      float acc = gemv1(sX, wp, DD, tid);
      if (m == 0)      stg_a(&P.qsa[(size_t)b * DD + col], acc + P.sa_bq[col]);
      else if (m == 1) stg_a(&P.Ksa[((size_t)b * TT + t) * DD + col], acc + P.sa_bk[col]);
      else if (m == 2) stg_a(&P.Vsa[((size_t)b * TT + t) * DD + col], acc + P.sa_bv[col]);
      else             stg_a(&P.qs[(size_t)b * DD + col], acc + P.s_bq[col]);
    }
    gsync(P.flags, P.rels, round, tid, bid);

    // ---- Phase B: spatial attn (b,h) + self-attn (b,h). h=bid&7 ------------
    {
      int b = bid >> 3, h = bid & 7;
      float* sP = sX + DD;
      float* sB = sX + 2 * DD;
      attn256_bf16(P.qs, b, h, P.KsTb, P.VsB, P.aSP + (size_t)b * DD,
                   sQh, sP, sB, redM, redS, tid);
      // self-attn, head h over L keys (fp32 cache, immutable rows)
      int L = t + 1;
      if (tid < DH) sQh[tid] = ldg_a(P.qsa + (size_t)b * DD + h * DH + tid);
      __syncthreads();
      float sc = -1e30f;
      if (tid < L) {
        const float* kp = P.Ksa + ((size_t)b * TT + tid) * DD + h * DH;
        float a = 0.f;
        #pragma unroll
        for (int i = 0; i < DH; i += 4) {
          float4 kv = *(const float4*)(kp + i);
          a += sQh[i] * kv.x + sQh[i + 1] * kv.y + sQh[i + 2] * kv.z + sQh[i + 3] * kv.w;
        }
        sc = a * 0.125f;
      }
      if (tid < 64) sP[tid] = sc;
      __syncthreads();
      if (tid < 64) {
        float v = sP[tid];
        float m = v;
        #pragma unroll
        for (int s = 32; s >= 1; s >>= 1) m = fmaxf(m, __shfl_xor(m, s));
        float e = (tid < L) ? __expf(v - m) : 0.f;
        float s2 = e;
        #pragma unroll
        for (int s = 32; s >= 1; s >>= 1) s2 += __shfl_xor(s2, s);
        sP[tid] = e;
        if (tid == 0) sInv[0] = 1.f / s2;
      }
      __syncthreads();
      int g = tid >> 6, d = tid & 63;
      float acc = 0.f;
      for (int j = g; j < L; j += 4)
        acc += sP[j] * P.Vsa[((size_t)b * TT + j) * DD + h * DH + d];
      sB[tid] = acc;
      __syncthreads();
      if (tid < 64)
        stg_a(P.aSA + (size_t)b * DD + h * DH + tid,
              (sB[tid] + sB[64 + tid] + sB[128 + tid] + sB[192 + tid]) * sInv[0]);
    }
    gsync(P.flags, P.rels, round, tid, bid);

    // ---- Phase C: u1 = aSA@saWo + sa_bo + x ; ctx = aSP@sWo + s_bo ---------
    if (bid < 128) {
      int cs = bid & 15, bg = bid >> 4;
      int mz = cs >> 3, jb = cs & 7;
      stage4a(sX, (mz ? P.aSP : P.aSA) + (size_t)(bg * 4) * DD, tid);
      __syncthreads();
      int col = jb * 64 + (tid & 63);
      int b = bg * 4 + (tid >> 6);
      const float* wp = P.wt8 + (size_t)(4 + mz) * DD * DD + col;  // 4:saWo 5:sWo
      float acc = gemv1(sX, wp, DD, tid);
      if (mz == 0)
        stg_a(&P.u1[(size_t)b * DD + col],
              acc + P.sa_bo[col] + ldg_a(&P.xcur[(size_t)b * DD + col]));
      else
        stg_a(&P.ctx[(size_t)b * DD + col], acc + P.s_bo[col]);
    }
    gsync(P.flags, P.rels, round, tid, bid);

    // ---- Phase D: LN1(u1) -> y1 (cs==0) ; qc = y1@caWq + ca_bq -------------
    if (bid < 64) {
      int cs = bid & 7, bg = bid >> 3;
      stage4a(sX, P.u1 + (size_t)(bg * 4) * DD, tid);
      __syncthreads();
      ln4(sX, P.ln1w, P.ln1b, lm, li, tid);
      if (cs == 0) {
        #pragma unroll
        for (int r = 0; r < 4; r++) {
          stg_a(&P.y1[(size_t)(bg * 4 + r) * DD + tid], sX[r * DD + tid]);
          stg_a(&P.y1[(size_t)(bg * 4 + r) * DD + tid + 256], sX[r * DD + tid + 256]);
        }
      }
      int col = cs * 64 + (tid & 63);
      int b = bg * 4 + (tid >> 6);
      const float* wp = P.wt8 + 6ull * DD * DD + col;  // 6:caWq
      float acc = gemv1(sX, wp, DD, tid);
      stg_a(&P.qc[(size_t)b * DD + col], acc + P.ca_bq[col]);
    }
    gsync(P.flags, P.rels, round, tid, bid);

    // ---- Phase E: cross-attn (b,h), h=bid&7 --------------------------------
    {
      int b = bid >> 3, h = bid & 7;
      attn256_bf16(P.qc, b, h, P.KcTb, P.VcB, P.aCA + (size_t)b * DD,
                   sQh, sX + DD, sX + 2 * DD, redM, redS, tid);
    }
    gsync(P.flags, P.rels, round, tid, bid);

    // ---- Phase F: u2 = aCA@caWo + ca_bo + y1 -------------------------------
    if (bid < 64) {
      int cs = bid & 7, bg = bid >> 3;
      stage4a(sX, P.aCA + (size_t)(bg * 4) * DD, tid);
      __syncthreads();
      int col = cs * 64 + (tid & 63);
      int b = bg * 4 + (tid >> 6);
      const float* wp = P.wt8 + 7ull * DD * DD + col;  // 7:caWo
      float acc = gemv1(sX, wp, DD, tid);
      stg_a(&P.u2[(size_t)b * DD + col],
            acc + P.ca_bo[col] + ldg_a(&P.y1[(size_t)b * DD + col]));
    }
    gsync(P.flags, P.rels, round, tid, bid);

    // ---- Phase G: LN2(u2)=z ; u3=z+b2 (cs==0) ; hbuf=relu(z@W1+b1) ---------
    {
      int cs = bid & 31, bg = bid >> 5;
      stage4a(sX, P.u2 + (size_t)(bg * 4) * DD, tid);
      __syncthreads();
      ln4(sX, P.ln2w, P.ln2b, lm, li, tid);
      if (cs == 0) {
        float f0 = P.b2[tid], f1 = P.b2[tid + 256];
        #pragma unroll
        for (int r = 0; r < 4; r++) {
          stg_a(&P.u3[(size_t)(bg * 4 + r) * DD + tid], sX[r * DD + tid] + f0);
          stg_a(&P.u3[(size_t)(bg * 4 + r) * DD + tid + 256], sX[r * DD + tid + 256] + f1);
        }
      }
      int col = cs * 64 + (tid & 63);   // [0,2048)
      int b = bg * 4 + (tid >> 6);
      const float* wp = P.W1t + col;
      float acc = gemv1(sX, wp, DF, tid);
      stg_a(&P.hbuf[(size_t)b * DF + col], fmaxf(acc + P.b1[col], 0.f));
    }
    gsync(P.flags, P.rels, round, tid, bid);

    // ---- Phase H: u3 += hbuf@W2 (split-k x4, device-scope atomics) ---------
    {
      int cs = bid & 7, ks = (bid >> 3) & 3, bg = bid >> 5;
      #pragma unroll
      for (int q = 0; q < 8; q++) {
        int f = q * 256 + tid, r = f >> 9, c = f & 511;
        sX[f] = ldg_a(&P.hbuf[(size_t)(bg * 4 + r) * DF + ks * 512 + c]);
      }
      __syncthreads();
      int col = cs * 64 + (tid & 63);
      int b = bg * 4 + (tid >> 6);
      const float* wp = P.W2t + (size_t)(ks * 512) * DD + col;
      float acc = gemv1(sX, wp, DD, tid);
      atomicAdd(&P.u3[(size_t)b * DD + col], acc);
    }
    gsync(P.flags, P.rels, round, tid, bid);

    // ---- Phase I: nxt = LN3(u3)+ctx ; out ; xcur = nxt + pe[t+1] -----------
    if (bid < NB) {
      int b = bid, wv = tid >> 6, lane = tid & 63;
      float u0 = ldg_a(&P.u3[(size_t)b * DD + tid]);
      float u1v = ldg_a(&P.u3[(size_t)b * DD + tid + 256]);
      float s = u0 + u1v, q = u0 * u0 + u1v * u1v;
      #pragma unroll
      for (int m = 32; m >= 1; m >>= 1) { s += __shfl_xor(s, m); q += __shfl_xor(q, m); }
      if (lane == 0) { red[wv] = s; red[8 + wv] = q; }
      __syncthreads();
      if (tid == 0) {
        float ss = red[0] + red[1] + red[2] + red[3];
        float qq = red[8] + red[9] + red[10] + red[11];
        float mm = ss * (1.0f / 512.0f);
        red[16] = mm;
        red[17] = rsqrtf(qq * (1.0f / 512.0f) - mm * mm + 1e-5f);
      }
      __syncthreads();
      float mean = red[16], inv = red[17];
      float n0 = (u0 - mean) * inv * P.ln3w[tid] + P.ln3b[tid] +
                 ldg_a(&P.ctx[(size_t)b * DD + tid]);
      float n1 = (u1v - mean) * inv * P.ln3w[tid + 256] + P.ln3b[tid + 256] +
                 ldg_a(&P.ctx[(size_t)b * DD + tid + 256]);
      sX[tid] = n0; sX[tid + 256] = n1;
      float p0 = (t < TT - 1) ? P.pe[(size_t)(t + 1) * DD + tid] : 0.f;
      float p1 = (t < TT - 1) ? P.pe[(size_t)(t + 1) * DD + tid + 256] : 0.f;
      stg_a(&P.xcur[(size_t)b * DD + tid], n0 + p0);
      stg_a(&P.xcur[(size_t)b * DD + tid + 256], n1 + p1);
      __syncthreads();
      int c = tid >> 7, l = tid & 127;
      float a = 0.f;
      #pragma unroll
      for (int i = 0; i < 4; i++)
        a += sX[l + i * 128] * P.Wout[(size_t)c * DD + l + i * 128];
      #pragma unroll
      for (int m = 32; m >= 1; m >>= 1) a += __shfl_xor(a, m);
      if ((tid & 63) == 0) red[tid >> 6] = a;
      __syncthreads();
      if (tid == 0)   P.out[((size_t)b * TT + t) * 2 + 0] = red[0] + red[1] + P.bout[0];
      if (tid == 128) P.out[((size_t)b * TT + t) * 2 + 1] = red[2] + red[3] + P.bout[1];
    }
    gsync(P.flags, P.rels, round, tid, bid);
  }
}

// ---- precompute kernels -----------------------------------------------------
struct TPItem { const float* in; float* out; int R; int C; };
struct TPArgs { TPItem m[10]; };

__global__ __launch_bounds__(256) void transpose_many(TPArgs args) {
  const TPItem t = args.m[blockIdx.z];
  int r0 = blockIdx.x * 32, c0 = blockIdx.y * 32;
  if (r0 >= t.R || c0 >= t.C) return;
  __shared__ float tile[32][33];
  int tid = threadIdx.x;
  int i = tid >> 3, j4 = (tid & 7) * 4;
  float4 v = *(const float4*)(t.in + (size_t)(r0 + i) * t.C + c0 + j4);
  tile[i][j4] = v.x; tile[i][j4 + 1] = v.y; tile[i][j4 + 2] = v.z; tile[i][j4 + 3] = v.w;
  __syncthreads();
  float4 o;
  o.x = tile[j4][i]; o.y = tile[j4 + 1][i]; o.z = tile[j4 + 2][i]; o.w = tile[j4 + 3][i];
  *(float4*)(t.out + (size_t)(c0 + i) * t.R + r0 + j4) = o;
}

// K fp32 [b][n][d] -> bf16 transposed [b][d][n]
__global__ __launch_bounds__(256) void pack_kT(const float* __restrict__ Ks32,
                                               const float* __restrict__ Kc32,
                                               ushort_t* __restrict__ KsTb,
                                               ushort_t* __restrict__ KcTb) {
  int z = blockIdx.z;
  int b = z >> 1;
  const float* in = ((z & 1) ? Kc32 : Ks32) + (size_t)b * NN * DD;
  ushort_t* out = ((z & 1) ? KcTb : KsTb) + (size_t)b * NN * DD;
  int r0 = blockIdx.x * 32, c0 = blockIdx.y * 32;  // r over n(256), c over d(512)
  __shared__ float tile[32][33];
  int tid = threadIdx.x;
  int i = tid >> 3, j4 = (tid & 7) * 4;
  float4 v = *(const float4*)(in + (size_t)(r0 + i) * DD + c0 + j4);
  tile[i][j4] = v.x; tile[i][j4 + 1] = v.y; tile[i][j4 + 2] = v.z; tile[i][j4 + 3] = v.w;
  __syncthreads();
  ushort_t* op = out + (size_t)(c0 + i) * NN + r0 + j4;
  op[0] = f2bf(tile[j4][i]); op[1] = f2bf(tile[j4 + 1][i]);
  op[2] = f2bf(tile[j4 + 2][i]); op[3] = f2bf(tile[j4 + 3][i]);
}

// V fp32 -> bf16 elementwise
__global__ __launch_bounds__(256) void conv_v(const float* __restrict__ Vs32,
                                              const float* __restrict__ Vc32,
                                              ushort_t* __restrict__ VsB,
                                              ushort_t* __restrict__ VcB) {
  const float* src = blockIdx.y ? Vc32 : Vs32;
  ushort_t* dst = blockIdx.y ? VcB : VsB;
  size_t base = (size_t)blockIdx.x * 2048;
  #pragma unroll
  for (int q = 0; q < 2; q++) {
    size_t i = base + q * 1024 + threadIdx.x * 4;
    float4 v = *(const float4*)(src + i);
    dst[i] = f2bf(v.x); dst[i + 1] = f2bf(v.y);
    dst[i + 2] = f2bf(v.z); dst[i + 3] = f2bf(v.w);
  }
}

__global__ __launch_bounds__(256) void init_x(const float* __restrict__ hv0,
                                              const float* __restrict__ pe,
                                              float* __restrict__ xcur,
                                              unsigned* __restrict__ flags) {
  int i = blockIdx.x * 256 + threadIdx.x;
  xcur[i] = hv0[i] + pe[i & (DD - 1)];
  if (i < NBLK * FLAG_STRIDE * 2) flags[i] = 0u;  // arrival flags + release slots
}

__global__ __launch_bounds__(256) void gemm_kv(
    const float* __restrict__ A,
    const float* __restrict__ W0, const float* __restrict__ W1_,
    const float* __restrict__ W2_, const float* __restrict__ W3_,
    const float* __restrict__ b0, const float* __restrict__ b1_,
    const float* __restrict__ b2_, const float* __restrict__ b3_,
    float* __restrict__ O0, float* __restrict__ O1,
    float* __restrict__ O2, float* __restrict__ O3) {
  __shared__ __align__(16) float As[8][128];
  __shared__ __align__(16) float Bs[8][128];
  int tid = threadIdx.x;
  int bx = blockIdx.x, by = blockIdx.y;
  int mm = bx >> 2;
  int col0 = (bx & 3) * 128;
  const float* W = mm == 0 ? W0 : mm == 1 ? W1_ : mm == 2 ? W2_ : W3_;
  const float* bias = mm == 0 ? b0 : mm == 1 ? b1_ : mm == 2 ? b2_ : b3_;
  float* O = mm == 0 ? O0 : mm == 1 ? O1 : mm == 2 ? O2 : O3;
  int tx = tid & 15, ty = tid >> 4;
  int m0 = by * 128;
  int lr = tid >> 1, lk = (tid & 1) * 4;
  const float* Ap = A + (size_t)(m0 + lr) * DD + lk;
  const float* Wp = W + (size_t)(col0 + lr) * DD + lk;
  float c[8][8] = {};
  for (int k0 = 0; k0 < DD; k0 += 8) {
    float4 av = *(const float4*)(Ap + k0);
    float4 wv = *(const float4*)(Wp + k0);
    __syncthreads();
    As[lk + 0][lr] = av.x; As[lk + 1][lr] = av.y; As[lk + 2][lr] = av.z; As[lk + 3][lr] = av.w;
    Bs[lk + 0][lr] = wv.x; Bs[lk + 1][lr] = wv.y; Bs[lk + 2][lr] = wv.z; Bs[lk + 3][lr] = wv.w;
    __syncthreads();
    #pragma unroll
    for (int k = 0; k < 8; k++) {
      float a[8], bb[8];
      *(float4*)&a[0] = *(const float4*)&As[k][ty * 8];
      *(float4*)&a[4] = *(const float4*)&As[k][ty * 8 + 4];
      *(float4*)&bb[0] = *(const float4*)&Bs[k][tx * 8];
      *(float4*)&bb[4] = *(const float4*)&Bs[k][tx * 8 + 4];
      #pragma unroll
      for (int i = 0; i < 8; i++)
        #pragma unroll
        for (int j = 0; j < 8; j++) c[i][j] += a[i] * bb[j];
    }
  }
  const float* bp = bias + col0 + tx * 8;
  for (int i = 0; i < 8; i++) {
    int row = m0 + ty * 8 + i;
    float* op = O + (size_t)row * DD + col0 + tx * 8;
    #pragma unroll
    for (int jq = 0; jq < 8; jq += 4) {
      float4 v;
      v.x = c[i][jq + 0] + bp[jq + 0];
      v.y = c[i][jq + 1] + bp[jq + 1];
      v.z = c[i][jq + 2] + bp[jq + 2];
      v.w = c[i][jq + 3] + bp[jq + 3];
      *(float4*)(op + jq) = v;
    }
  }
}

// ---------------------------------------------------------------------------
extern "C" void kernel_launch(void* const* d_in, const int* in_sizes, int n_in,
                              void* d_out, int out_size, void* d_ws, size_t ws_size,
                              hipStream_t stream) {
  const float* H_v_all = (const float*)d_in[0];
  const float* H_v0    = (const float*)d_in[1];
  const float* pe      = (const float*)d_in[2];
  const float* s_Wq = (const float*)d_in[3];
  const float* s_Wk = (const float*)d_in[4];
  const float* s_Wv = (const float*)d_in[5];
  const float* s_Wo = (const float*)d_in[6];
  const float* s_bq = (const float*)d_in[7];
  const float* s_bk = (const float*)d_in[8];
  const float* s_bv = (const float*)d_in[9];
  const float* s_bo = (const float*)d_in[10];
  const float* sa_Wq = (const float*)d_in[11];
  const float* sa_Wk = (const float*)d_in[12];
  const float* sa_Wv = (const float*)d_in[13];
  const float* sa_Wo = (const float*)d_in[14];
  const float* sa_bq = (const float*)d_in[15];
  const float* sa_bk = (const float*)d_in[16];
  const float* sa_bv = (const float*)d_in[17];
  const float* sa_bo = (const float*)d_in[18];
  const float* ca_Wq = (const float*)d_in[19];
  const float* ca_Wk = (const float*)d_in[20];
  const float* ca_Wv = (const float*)d_in[21];
  const float* ca_Wo = (const float*)d_in[22];
  const float* ca_bq = (const float*)d_in[23];
  const float* ca_bk = (const float*)d_in[24];
  const float* ca_bv = (const float*)d_in[25];
  const float* ca_bo = (const float*)d_in[26];
  const float* ln1w = (const float*)d_in[27];
  const float* ln1b = (const float*)d_in[28];
  const float* ln2w = (const float*)d_in[29];
  const float* ln2b = (const float*)d_in[30];
  const float* ln3w = (const float*)d_in[31];
  const float* ln3b = (const float*)d_in[32];
  const float* W1   = (const float*)d_in[33];
  const float* b1   = (const float*)d_in[34];
  const float* W2   = (const float*)d_in[35];
  const float* b2   = (const float*)d_in[36];
  const float* Wout = (const float*)d_in[37];
  const float* bout = (const float*)d_in[38];

  float* ws = (float*)d_ws;
  float* Ks32 = ws + OFF_KS32;
  float* Vs32 = ws + OFF_VS32;
  float* Kc32 = ws + OFF_KC32;
  float* Vc32 = ws + OFF_VC32;
  ushort_t* ub = (ushort_t*)(ws + OFF_BF);
  ushort_t* KsTb = ub + UOFF_KST;
  ushort_t* KcTb = ub + UOFF_KCT;
  ushort_t* VsB  = ub + UOFF_VS;
  ushort_t* VcB  = ub + UOFF_VC;
  float* wt8 = ws + OFF_WT;
  float* W1t = ws + OFF_W1T;
  float* W2t = ws + OFF_W2T;
  unsigned* flags = (unsigned*)(ws + OFF_FLG);

  // --- precompute -----------------------------------------------------------
  TPArgs tp;
  tp.m[0] = {sa_Wq, wt8 + 0ull * DD * DD, DD, DD};
  tp.m[1] = {sa_Wk, wt8 + 1ull * DD * DD, DD, DD};
  tp.m[2] = {sa_Wv, wt8 + 2ull * DD * DD, DD, DD};
  tp.m[3] = {s_Wq,  wt8 + 3ull * DD * DD, DD, DD};
  tp.m[4] = {sa_Wo, wt8 + 4ull * DD * DD, DD, DD};
  tp.m[5] = {s_Wo,  wt8 + 5ull * DD * DD, DD, DD};
  tp.m[6] = {ca_Wq, wt8 + 6ull * DD * DD, DD, DD};
  tp.m[7] = {ca_Wo, wt8 + 7ull * DD * DD, DD, DD};
  tp.m[8] = {W1, W1t, DF, DD};
  tp.m[9] = {W2, W2t, DD, DF};
  hipLaunchKernelGGL(transpose_many, dim3(64, 64, 10), dim3(256), 0, stream, tp);

  hipLaunchKernelGGL(gemm_kv, dim3(16, 64), dim3(256), 0, stream,
                     H_v_all, s_Wk, s_Wv, ca_Wk, ca_Wv,
                     s_bk, s_bv, ca_bk, ca_bv, Ks32, Vs32, Kc32, Vc32);

  hipLaunchKernelGGL(pack_kT, dim3(8, 16, 64), dim3(256), 0, stream,
                     Ks32, Kc32, KsTb, KcTb);
  hipLaunchKernelGGL(conv_v, dim3((unsigned)(SZ_KV / 2048), 2), dim3(256), 0, stream,
                     Vs32, Vc32, VsB, VcB);

  hipLaunchKernelGGL(init_x, dim3(64), dim3(256), 0, stream,
                     H_v0, pe, ws + OFF_X, flags);

  // --- persistent decode ----------------------------------------------------
  Params P;
  P.pe = pe;
  P.sa_bq = sa_bq; P.sa_bk = sa_bk; P.sa_bv = sa_bv; P.sa_bo = sa_bo;
  P.s_bq = s_bq; P.s_bo = s_bo; P.ca_bq = ca_bq; P.ca_bo = ca_bo;
  P.ln1w = ln1w; P.ln1b = ln1b; P.ln2w = ln2w; P.ln2b = ln2b;
  P.ln3w = ln3w; P.ln3b = ln3b;
  P.b1 = b1; P.b2 = b2; P.Wout = Wout; P.bout = bout;
  P.wt8 = wt8; P.W1t = W1t; P.W2t = W2t;
  P.KsTb = KsTb; P.KcTb = KcTb; P.VsB = VsB; P.VcB = VcB;
  P.Ksa = ws + OFF_KSA; P.Vsa = ws + OFF_VSA;
  P.xcur = ws + OFF_X;
  P.qsa = ws + OFF_QSA; P.qs = ws + OFF_QS;
  P.aSA = ws + OFF_ASA; P.aSP = ws + OFF_ASP; P.aCA = ws + OFF_ACA;
  P.u1 = ws + OFF_U1; P.y1 = ws + OFF_Y1; P.qc = ws + OFF_QC;
  P.u2 = ws + OFF_U2; P.ctx = ws + OFF_CTX; P.u3 = ws + OFF_U3;
  P.hbuf = ws + OFF_H;
  P.out = (float*)d_out;
  P.flags = flags;
  P.rels = flags + (size_t)NBLK * FLAG_STRIDE;

  void* kargs[] = { (void*)&P };
  hipLaunchCooperativeKernel((void*)decode_persistent, dim3(NBLK), dim3(256),
                             kargs, 0, stream);
}

// Round 7
// 7052.797 us; speedup vs baseline: 1.1611x; 1.1611x over previous
//
#include <hip/hip_runtime.h>

// ---------------------------------------------------------------------------
// VehicleTrajectoryDecoder: B=32, N=256, D=512, H=8 (dh=64), T=60, DFF=2048.
// R7: R6 counters: FETCH 1.78GB/dispatch = ~30MB/step = whole working set
// refetched each step at 246GB/s => time = bytes/246GB/s. Per-XCD L2 (4MB)
// thrashes (head-sliced KV alone = 4MB/XCD). Fix: bf16 weights (8MB) +
// bf16 head-private self-KV + XCD-stable slicing (everything a block touches
// is a function of bid&7) -> ~3.5MB/XCD, L2-resident across steps. Phases
// merged 9->7 (proj into attn; LN1+caWq into cross-attn). Flags packed.
// ---------------------------------------------------------------------------

#define NB 32
#define NN 256
#define DD 512
#define NH 8
#define DH 64
#define TT 60
#define DF 2048
#define NBLK 256

typedef unsigned short ushort_t;

// ---- workspace layout ------------------------------------------------------
constexpr size_t SZ_KV  = (size_t)NB * NN * DD;   // 4194304
constexpr size_t SZ_ROW = (size_t)NB * DD;        // 16384
constexpr size_t SZ_SAB = (size_t)NB * NH * TT * DH;  // 983040
// fp32 precompute scratch (dead before decode):
constexpr size_t OFF_KS32 = 0;
constexpr size_t OFF_VS32 = SZ_KV;
constexpr size_t OFF_KC32 = 2 * SZ_KV;
constexpr size_t OFF_VC32 = 3 * SZ_KV;
// decode-time activation overlay (fp32, inside dead scratch):
constexpr size_t OFF_X   = 0;
constexpr size_t OFF_ASA = OFF_X   + SZ_ROW;
constexpr size_t OFF_ASP = OFF_ASA + SZ_ROW;
constexpr size_t OFF_ACA = OFF_ASP + SZ_ROW;
constexpr size_t OFF_U1  = OFF_ACA + SZ_ROW;
constexpr size_t OFF_Y1  = OFF_U1  + SZ_ROW;
constexpr size_t OFF_U2  = OFF_Y1  + SZ_ROW;
constexpr size_t OFF_CTX = OFF_U2  + SZ_ROW;
constexpr size_t OFF_U3  = OFF_CTX + SZ_ROW;
constexpr size_t OFF_H   = OFF_U3  + SZ_ROW;      // hbuf [32][2048]
// bf16 region (ushort indices from ub):
constexpr size_t OFF_BF   = 4 * SZ_KV;            // float offset of ushort base
constexpr size_t UOFF_KST = 0;                    // KsT [b][d][n]
constexpr size_t UOFF_KCT = SZ_KV;                // KcT [b][d][n]
constexpr size_t UOFF_VSH = 2 * SZ_KV;            // Vs  [b][h][n][64]
constexpr size_t UOFF_VCH = 3 * SZ_KV;            // Vc  [b][h][n][64]
constexpr size_t UOFF_KSA = 4 * SZ_KV;            // self K cache [b*8+h][t][64]
constexpr size_t UOFF_VSA = UOFF_KSA + SZ_SAB;
constexpr size_t UOFF_W8  = UOFF_VSA + SZ_SAB;    // 8 x 512x512 packed
constexpr size_t UOFF_W1  = UOFF_W8 + 8ull * DD * DD;     // [512x2048] packed
constexpr size_t UOFF_W2  = UOFF_W1 + (size_t)DD * DF;    // [2048x512] packed
constexpr size_t UEND     = UOFF_W2 + (size_t)DF * DD;
constexpr size_t OFF_FLG  = OFF_BF + (UEND + 1) / 2;      // u32 flags
// flags: arrival u32[256] at 0, release u32[256] at 512. total ws ~113.5MB

// ---- helpers ----------------------------------------------------------------
__device__ __forceinline__ float ldg_a(const float* p) {
  return __hip_atomic_load(p, __ATOMIC_RELAXED, __HIP_MEMORY_SCOPE_AGENT);
}
__device__ __forceinline__ void stg_a(float* p, float v) {
  __hip_atomic_store(p, v, __ATOMIC_RELAXED, __HIP_MEMORY_SCOPE_AGENT);
}
__device__ __forceinline__ float bf2f(ushort_t u) {
  return __uint_as_float(((unsigned)u) << 16);
}
__device__ __forceinline__ ushort_t f2bf(float f) {
  unsigned u = __float_as_uint(f);
  return (ushort_t)((u + 0x7FFFu + ((u >> 16) & 1u)) >> 16);
}

// ---- params ----------------------------------------------------------------
struct Params {
  const float *pe;
  const float *sa_bq, *sa_bk, *sa_bv, *s_bq, *sa_bo, *s_bo, *ca_bq, *ca_bo;
  const float *ln1w, *ln1b, *ln2w, *ln2b, *ln3w, *ln3b;
  const float *b1, *b2, *Wout, *bout;
  const ushort_t *w8, *w1b, *w2b;      // bf16 packed weights
  const ushort_t *KsT, *KcT, *VsH, *VcH;
  ushort_t *KsaB, *VsaB;               // head-private self KV (plain access)
  float *xcur, *aSA, *aSP, *aCA, *u1, *y1, *u2, *ctx, *u3, *hbuf;
  float *out;
  unsigned *flags, *rels;              // packed 4B flags
};

// ---- grid barrier: packed flags, leader-poll, parallel packed release -------
__device__ __forceinline__ void gsync(unsigned* flags, unsigned* rels,
                                      unsigned& round, int tid, int bid) {
  __builtin_amdgcn_s_waitcnt(0);
  __syncthreads();
  round++;
  if (bid == 0) {
    if (tid > 0) {
      while (__hip_atomic_load(&flags[tid], __ATOMIC_RELAXED,
                               __HIP_MEMORY_SCOPE_AGENT) < round)
        __builtin_amdgcn_s_sleep(1);
    }
    __syncthreads();
    __hip_atomic_store(&rels[tid], round, __ATOMIC_RELAXED,
                       __HIP_MEMORY_SCOPE_AGENT);
  } else if (tid == 0) {
    __hip_atomic_store(&flags[bid], round, __ATOMIC_RELAXED,
                       __HIP_MEMORY_SCOPE_AGENT);
    while (__hip_atomic_load(&rels[bid], __ATOMIC_RELAXED,
                             __HIP_MEMORY_SCOPE_AGENT) < round)
      __builtin_amdgcn_s_sleep(1);
  }
  __syncthreads();
}

// GEMV over 512 k, bf16 ushort4-packed weights [k/4][C][4], x row in LDS.
__device__ __forceinline__ float gemv_bf(const float* xr, const ushort_t* wbase,
                                         int col, int C) {
  const ushort4* wp = (const ushort4*)wbase + col;
  float acc = 0.f;
  #pragma unroll 4
  for (int kq = 0; kq < 128; kq++) {
    ushort4 wv = wp[(size_t)kq * C];
    float4 xv = *(const float4*)(xr + kq * 4);
    acc += xv.x * bf2f(wv.x) + xv.y * bf2f(wv.y) +
           xv.z * bf2f(wv.z) + xv.w * bf2f(wv.w);
  }
  return acc;
}

// attention over 256 keys for one (b,h): sQ LDS[64], KT=[d][n] base(b,h applied
// via offset), Vh=[n][64] base. Writes 64 outputs via sc1.
__device__ __forceinline__ void attn256(const float* sQ, const ushort_t* KT,
                                        const ushort_t* Vh, float* outp,
                                        float* sPb, float* sB, float* sAux,
                                        int tid) {
  __syncthreads();
  const ushort_t* kp = KT + tid;
  float a = 0.f;
  #pragma unroll 8
  for (int i = 0; i < DH; i++) a += sQ[i] * bf2f(kp[(size_t)i * NN]);
  a *= 0.125f;
  int w = tid >> 6, lane = tid & 63;
  float mx = a;
  #pragma unroll
  for (int s = 32; s >= 1; s >>= 1) mx = fmaxf(mx, __shfl_xor(mx, s));
  if (lane == 0) sAux[w] = mx;
  __syncthreads();
  mx = fmaxf(fmaxf(sAux[0], sAux[1]), fmaxf(sAux[2], sAux[3]));
  float e = __expf(a - mx);
  float ss = e;
  #pragma unroll
  for (int s = 32; s >= 1; s >>= 1) ss += __shfl_xor(ss, s);
  if (lane == 0) sAux[4 + w] = ss;
  sPb[tid] = e;
  __syncthreads();
  float inv = 1.f / (sAux[4] + sAux[5] + sAux[6] + sAux[7]);
  int g = tid >> 6, d = tid & 63;
  const ushort_t* vp = Vh + (size_t)(g * 64) * DH + d;
  float acc = 0.f;
  #pragma unroll 4
  for (int n = 0; n < 64; n++) acc += sPb[g * 64 + n] * bf2f(vp[(size_t)n * DH]);
  sB[tid] = acc;
  __syncthreads();
  if (tid < 64)
    stg_a(outp + tid, (sB[tid] + sB[64 + tid] + sB[128 + tid] + sB[192 + tid]) * inv);
  __syncthreads();
}

// ---- persistent decode ------------------------------------------------------
__global__ __launch_bounds__(256) void decode_persistent(Params P) {
  __shared__ __align__(16) float sX[2048];  // 8KB
  __shared__ float sAux[64];
  int tid = threadIdx.x;
  int bid = blockIdx.x;
  unsigned round = 0;

  for (int t = 0; t < TT; t++) {
    // ==== Phase 1: per-(b,h) proj(q,k,v,qs head slices) + self-attn + spatial
    {
      int b = bid >> 3, h = bid & 7;
      sX[tid] = ldg_a(P.xcur + (size_t)b * DD + tid);
      sX[256 + tid] = ldg_a(P.xcur + (size_t)b * DD + 256 + tid);
      __syncthreads();
      // proj: wave m: 0=q_self(saWq) 1=k(saWk) 2=v(saWv) 3=q_spatial(sWq)
      int m = tid >> 6, c = tid & 63, col = h * DH + c;
      float acc = gemv_bf(sX, P.w8 + (size_t)m * DD * DD, col, DD);
      const float* bias = (m == 0) ? P.sa_bq : (m == 1) ? P.sa_bk
                        : (m == 2) ? P.sa_bv : P.s_bq;
      float val = acc + bias[col];
      sX[512 + tid] = val;  // sP4: [0,64)=q_self [192,256)=q_spatial
      if (m == 1) P.KsaB[((size_t)bid * TT + t) * DH + c] = f2bf(val);
      if (m == 2) P.VsaB[((size_t)bid * TT + t) * DH + c] = f2bf(val);
      __syncthreads();

      // self-attn over L keys (head-private bf16 cache, plain loads)
      int L = t + 1;
      float* sQ  = sX + 512;
      float* sQs = sX + 512 + 192;
      float* sPb = sX + 768;
      float* sB  = sX + 1024;
      float sc = -1e30f;
      if (tid < L) {
        const ushort_t* kp = P.KsaB + ((size_t)bid * TT + tid) * DH;
        float a = 0.f;
        #pragma unroll
        for (int i = 0; i < DH; i += 4) {
          ushort4 kv = *(const ushort4*)(kp + i);
          a += sQ[i] * bf2f(kv.x) + sQ[i + 1] * bf2f(kv.y) +
               sQ[i + 2] * bf2f(kv.z) + sQ[i + 3] * bf2f(kv.w);
        }
        sc = a * 0.125f;
      }
      if (tid < 64) {
        float mx = sc;
        #pragma unroll
        for (int s = 32; s >= 1; s >>= 1) mx = fmaxf(mx, __shfl_xor(mx, s));
        float e = (tid < L) ? __expf(sc - mx) : 0.f;
        float s2 = e;
        #pragma unroll
        for (int s = 32; s >= 1; s >>= 1) s2 += __shfl_xor(s2, s);
        sPb[tid] = e;
        if (tid == 0) sAux[8] = 1.f / s2;
      }
      __syncthreads();
      {
        int g = tid >> 6, d = tid & 63;
        float a2 = 0.f;
        for (int j = g; j < L; j += 4)
          a2 += sPb[j] * bf2f(P.VsaB[((size_t)bid * TT + j) * DH + d]);
        sB[tid] = a2;
      }
      __syncthreads();
      if (tid < 64)
        stg_a(&P.aSA[(size_t)b * DD + h * DH + tid],
              (sB[tid] + sB[64 + tid] + sB[128 + tid] + sB[192 + tid]) * sAux[8]);
      // spatial attention (head-pinned KV, L2-resident)
      attn256(sQs, P.KsT + ((size_t)b * DD + h * DH) * NN,
              P.VsH + (size_t)bid * NN * DH,
              &P.aSP[(size_t)b * DD + h * DH], sPb, sB, sAux, tid);
    }
    gsync(P.flags, P.rels, round, tid, bid);

    // ==== Phase 2: u1 = aSA@saWo + sa_bo + x ; ctx = aSP@sWo + s_bo =========
    if (bid < 128) {
      int s = bid & 7, mz = (bid >> 3) & 1, bg = bid >> 4;
      const float* src = (mz ? P.aSP : P.aSA) + (size_t)bg * 4 * DD;
      #pragma unroll
      for (int q = 0; q < 8; q++) sX[q * 256 + tid] = ldg_a(src + q * 256 + tid);
      __syncthreads();
      int c = tid & 63, r = tid >> 6, b = bg * 4 + r, col = s * DH + c;
      float acc = gemv_bf(sX + r * DD, P.w8 + (size_t)(4 + mz) * DD * DD, col, DD);
      if (mz == 0)
        stg_a(&P.u1[(size_t)b * DD + col],
              acc + P.sa_bo[col] + ldg_a(&P.xcur[(size_t)b * DD + col]));
      else
        stg_a(&P.ctx[(size_t)b * DD + col], acc + P.s_bo[col]);
    }
    gsync(P.flags, P.rels, round, tid, bid);

    // ==== Phase 3: LN1(u1) -> y1(h==0) ; qc head ; cross-attn ===============
    {
      int b = bid >> 3, h = bid & 7;
      sX[tid] = ldg_a(P.u1 + (size_t)b * DD + tid);
      sX[256 + tid] = ldg_a(P.u1 + (size_t)b * DD + 256 + tid);
      __syncthreads();
      float v0 = sX[tid], v1 = sX[256 + tid];
      float s = v0 + v1, q2 = v0 * v0 + v1 * v1;
      int w = tid >> 6, lane = tid & 63;
      #pragma unroll
      for (int m = 32; m >= 1; m >>= 1) { s += __shfl_xor(s, m); q2 += __shfl_xor(q2, m); }
      if (lane == 0) { sAux[w] = s; sAux[4 + w] = q2; }
      __syncthreads();
      float mean = (sAux[0] + sAux[1] + sAux[2] + sAux[3]) * (1.f / 512.f);
      float inv = rsqrtf((sAux[4] + sAux[5] + sAux[6] + sAux[7]) * (1.f / 512.f)
                         - mean * mean + 1e-5f);
      float y0 = (v0 - mean) * inv * P.ln1w[tid] + P.ln1b[tid];
      float y1v = (v1 - mean) * inv * P.ln1w[256 + tid] + P.ln1b[256 + tid];
      __syncthreads();
      sX[tid] = y0; sX[256 + tid] = y1v;
      if (h == 0) {
        stg_a(&P.y1[(size_t)b * DD + tid], y0);
        stg_a(&P.y1[(size_t)b * DD + 256 + tid], y1v);
      }
      __syncthreads();
      // qc head: col c, k-chunk g of 128
      int c = tid & 63, g = tid >> 6;
      const ushort4* wp = (const ushort4*)(P.w8 + 6ull * DD * DD) + (h * DH + c);
      float acc = 0.f;
      #pragma unroll 4
      for (int kq = g * 32; kq < g * 32 + 32; kq++) {
        ushort4 wv = wp[(size_t)kq * DD];
        float4 xv = *(const float4*)(sX + kq * 4);
        acc += xv.x * bf2f(wv.x) + xv.y * bf2f(wv.y) +
               xv.z * bf2f(wv.z) + xv.w * bf2f(wv.w);
      }
      float* sB = sX + 1024;
      sB[tid] = acc;
      __syncthreads();
      if (tid < 64)
        sX[512 + tid] = sB[tid] + sB[64 + tid] + sB[128 + tid] + sB[192 + tid]
                        + P.ca_bq[h * DH + tid];
      attn256(sX + 512, P.KcT + ((size_t)b * DD + h * DH) * NN,
              P.VcH + (size_t)bid * NN * DH,
              &P.aCA[(size_t)b * DD + h * DH], sX + 768, sB, sAux, tid);
    }
    gsync(P.flags, P.rels, round, tid, bid);

    // ==== Phase 4: u2 = aCA@caWo + ca_bo + y1 ===============================
    if (bid < 64) {
      int s = bid & 7, bg = bid >> 3;
      const float* src = P.aCA + (size_t)bg * 4 * DD;
      #pragma unroll
      for (int q = 0; q < 8; q++) sX[q * 256 + tid] = ldg_a(src + q * 256 + tid);
      __syncthreads();
      int c = tid & 63, r = tid >> 6, b = bg * 4 + r, col = s * DH + c;
      float acc = gemv_bf(sX + r * DD, P.w8 + 7ull * DD * DD, col, DD);
      stg_a(&P.u2[(size_t)b * DD + col],
            acc + P.ca_bo[col] + ldg_a(&P.y1[(size_t)b * DD + col]));
    }
    gsync(P.flags, P.rels, round, tid, bid);

    // ==== Phase 5: LN2(u2)=z ; u3=z+b2 (c0==0) ; hbuf=relu(z@W1+b1) =========
    {
      int c0 = (bid & 7) * 64 + ((bid >> 3) & 3) * 512;
      int bg = bid >> 5;
      const float* src = P.u2 + (size_t)bg * 4 * DD;
      #pragma unroll
      for (int q = 0; q < 8; q++) sX[q * 256 + tid] = ldg_a(src + q * 256 + tid);
      __syncthreads();
      {  // LN of 4 rows, wave per row
        int wv = tid >> 6, lane = tid & 63;
        float s = 0.f, q2 = 0.f;
        #pragma unroll
        for (int i = 0; i < 8; i++) {
          float v = sX[wv * DD + lane + i * 64];
          s += v; q2 += v * v;
        }
        #pragma unroll
        for (int m = 32; m >= 1; m >>= 1) { s += __shfl_xor(s, m); q2 += __shfl_xor(q2, m); }
        if (lane == 0) {
          float mm = s * (1.f / 512.f);
          sAux[wv] = mm;
          sAux[4 + wv] = rsqrtf(q2 * (1.f / 512.f) - mm * mm + 1e-5f);
        }
        __syncthreads();
        float w0 = P.ln2w[tid], w1 = P.ln2w[256 + tid];
        float b0 = P.ln2b[tid], b1v = P.ln2b[256 + tid];
        #pragma unroll
        for (int r = 0; r < 4; r++) {
          sX[r * DD + tid] = (sX[r * DD + tid] - sAux[r]) * sAux[4 + r] * w0 + b0;
          sX[r * DD + 256 + tid] = (sX[r * DD + 256 + tid] - sAux[r]) * sAux[4 + r] * w1 + b1v;
        }
        __syncthreads();
      }
      if ((bid & 31) == 0) {
        float f0 = P.b2[tid], f1 = P.b2[256 + tid];
        #pragma unroll
        for (int r = 0; r < 4; r++) {
          stg_a(&P.u3[(size_t)(bg * 4 + r) * DD + tid], sX[r * DD + tid] + f0);
          stg_a(&P.u3[(size_t)(bg * 4 + r) * DD + 256 + tid], sX[r * DD + 256 + tid] + f1);
        }
      }
      int c = tid & 63, r = tid >> 6, b = bg * 4 + r, col = c0 + c;
      float acc = gemv_bf(sX + r * DD, P.w1b, col, DF);
      stg_a(&P.hbuf[(size_t)b * DF + col], fmaxf(acc + P.b1[col], 0.f));
    }
    gsync(P.flags, P.rels, round, tid, bid);

    // ==== Phase 6: u3 += hbuf@W2 (split-k x4, atomics) ======================
    {
      int col = (bid & 7) * 64 + (tid & 63);
      int ks = (bid >> 3) & 3, bg = bid >> 5;
      int k0 = ks * 512;
      #pragma unroll
      for (int q = 0; q < 8; q++) {
        int f = q * 256 + tid, rr = f >> 9, cc = f & 511;
        sX[f] = ldg_a(&P.hbuf[(size_t)(bg * 4 + rr) * DF + k0 + cc]);
      }
      __syncthreads();
      int r = tid >> 6, b = bg * 4 + r;
      const ushort4* wp = (const ushort4*)P.w2b + (size_t)(k0 >> 2) * DD + col;
      const float* xr = sX + r * DD;
      float acc = 0.f;
      #pragma unroll 4
      for (int kq = 0; kq < 128; kq++) {
        ushort4 wv = wp[(size_t)kq * DD];
        float4 xv = *(const float4*)(xr + kq * 4);
        acc += xv.x * bf2f(wv.x) + xv.y * bf2f(wv.y) +
               xv.z * bf2f(wv.z) + xv.w * bf2f(wv.w);
      }
      atomicAdd(&P.u3[(size_t)b * DD + col], acc);
    }
    gsync(P.flags, P.rels, round, tid, bid);

    // ==== Phase 7: nxt = LN3(u3)+ctx ; out ; xcur = nxt + pe[t+1] ===========
    if (bid < NB) {
      int b = bid, w = tid >> 6, lane = tid & 63;
      float u0 = ldg_a(&P.u3[(size_t)b * DD + tid]);
      float u1v = ldg_a(&P.u3[(size_t)b * DD + 256 + tid]);
      float s = u0 + u1v, q2 = u0 * u0 + u1v * u1v;
      #pragma unroll
      for (int m = 32; m >= 1; m >>= 1) { s += __shfl_xor(s, m); q2 += __shfl_xor(q2, m); }
      if (lane == 0) { sAux[w] = s; sAux[4 + w] = q2; }
      __syncthreads();
      float mean = (sAux[0] + sAux[1] + sAux[2] + sAux[3]) * (1.f / 512.f);
      float inv = rsqrtf((sAux[4] + sAux[5] + sAux[6] + sAux[7]) * (1.f / 512.f)
                         - mean * mean + 1e-5f);
      float n0 = (u0 - mean) * inv * P.ln3w[tid] + P.ln3b[tid] +
                 ldg_a(&P.ctx[(size_t)b * DD + tid]);
      float n1 = (u1v - mean) * inv * P.ln3w[256 + tid] + P.ln3b[256 + tid] +
                 ldg_a(&P.ctx[(size_t)b * DD + 256 + tid]);
      __syncthreads();
      sX[tid] = n0; sX[256 + tid] = n1;
      float p0 = (t < TT - 1) ? P.pe[(size_t)(t + 1) * DD + tid] : 0.f;
      float p1 = (t < TT - 1) ? P.pe[(size_t)(t + 1) * DD + 256 + tid] : 0.f;
      stg_a(&P.xcur[(size_t)b * DD + tid], n0 + p0);
      stg_a(&P.xcur[(size_t)b * DD + 256 + tid], n1 + p1);
      __syncthreads();
      int c = tid >> 7, l = tid & 127;
      float a = 0.f;
      #pragma unroll
      for (int i = 0; i < 4; i++)
        a += sX[l + i * 128] * P.Wout[(size_t)c * DD + l + i * 128];
      #pragma unroll
      for (int m = 32; m >= 1; m >>= 1) a += __shfl_xor(a, m);
      if ((tid & 63) == 0) sAux[8 + (tid >> 6)] = a;
      __syncthreads();
      if (tid == 0)   P.out[((size_t)b * TT + t) * 2 + 0] = sAux[8] + sAux[9] + P.bout[0];
      if (tid == 128) P.out[((size_t)b * TT + t) * 2 + 1] = sAux[10] + sAux[11] + P.bout[1];
    }
    gsync(P.flags, P.rels, round, tid, bid);
  }
}

// ---- precompute kernels -----------------------------------------------------
__global__ __launch_bounds__(256) void gemm_kv(
    const float* __restrict__ A,
    const float* __restrict__ W0, const float* __restrict__ W1_,
    const float* __restrict__ W2_, const float* __restrict__ W3_,
    const float* __restrict__ b0, const float* __restrict__ b1_,
    const float* __restrict__ b2_, const float* __restrict__ b3_,
    float* __restrict__ O0, float* __restrict__ O1,
    float* __restrict__ O2, float* __restrict__ O3) {
  __shared__ __align__(16) float As[8][128];
  __shared__ __align__(16) float Bs[8][128];
  int tid = threadIdx.x;
  int bx = blockIdx.x, by = blockIdx.y;
  int mm = bx >> 2;
  int col0 = (bx & 3) * 128;
  const float* W = mm == 0 ? W0 : mm == 1 ? W1_ : mm == 2 ? W2_ : W3_;
  const float* bias = mm == 0 ? b0 : mm == 1 ? b1_ : mm == 2 ? b2_ : b3_;
  float* O = mm == 0 ? O0 : mm == 1 ? O1 : mm == 2 ? O2 : O3;
  int tx = tid & 15, ty = tid >> 4;
  int m0 = by * 128;
  int lr = tid >> 1, lk = (tid & 1) * 4;
  const float* Ap = A + (size_t)(m0 + lr) * DD + lk;
  const float* Wp = W + (size_t)(col0 + lr) * DD + lk;
  float c[8][8] = {};
  for (int k0 = 0; k0 < DD; k0 += 8) {
    float4 av = *(const float4*)(Ap + k0);
    float4 wv = *(const float4*)(Wp + k0);
    __syncthreads();
    As[lk + 0][lr] = av.x; As[lk + 1][lr] = av.y; As[lk + 2][lr] = av.z; As[lk + 3][lr] = av.w;
    Bs[lk + 0][lr] = wv.x; Bs[lk + 1][lr] = wv.y; Bs[lk + 2][lr] = wv.z; Bs[lk + 3][lr] = wv.w;
    __syncthreads();
    #pragma unroll
    for (int k = 0; k < 8; k++) {
      float a[8], bb[8];
      *(float4*)&a[0] = *(const float4*)&As[k][ty * 8];
      *(float4*)&a[4] = *(const float4*)&As[k][ty * 8 + 4];
      *(float4*)&bb[0] = *(const float4*)&Bs[k][tx * 8];
      *(float4*)&bb[4] = *(const float4*)&Bs[k][tx * 8 + 4];
      #pragma unroll
      for (int i = 0; i < 8; i++)
        #pragma unroll
        for (int j = 0; j < 8; j++) c[i][j] += a[i] * bb[j];
    }
  }
  const float* bp = bias + col0 + tx * 8;
  for (int i = 0; i < 8; i++) {
    int row = m0 + ty * 8 + i;
    float* op = O + (size_t)row * DD + col0 + tx * 8;
    #pragma unroll
    for (int jq = 0; jq < 8; jq += 4) {
      float4 v;
      v.x = c[i][jq + 0] + bp[jq + 0];
      v.y = c[i][jq + 1] + bp[jq + 1];
      v.z = c[i][jq + 2] + bp[jq + 2];
      v.w = c[i][jq + 3] + bp[jq + 3];
      *(float4*)(op + jq) = v;
    }
  }
}

// K fp32 [b][n][d] -> bf16 [b][d][n]
__global__ __launch_bounds__(256) void pack_kT(const float* __restrict__ Ks32,
                                               const float* __restrict__ Kc32,
                                               ushort_t* __restrict__ KsT,
                                               ushort_t* __restrict__ KcT) {
  int z = blockIdx.z;
  int b = z >> 1;
  const float* in = ((z & 1) ? Kc32 : Ks32) + (size_t)b * NN * DD;
  ushort_t* out = ((z & 1) ? KcT : KsT) + (size_t)b * NN * DD;
  int r0 = blockIdx.x * 32, c0 = blockIdx.y * 32;
  __shared__ float tile[32][33];
  int tid = threadIdx.x;
  int i = tid >> 3, j4 = (tid & 7) * 4;
  float4 v = *(const float4*)(in + (size_t)(r0 + i) * DD + c0 + j4);
  tile[i][j4] = v.x; tile[i][j4 + 1] = v.y; tile[i][j4 + 2] = v.z; tile[i][j4 + 3] = v.w;
  __syncthreads();
  ushort_t* op = out + (size_t)(c0 + i) * NN + r0 + j4;
  op[0] = f2bf(tile[j4][i]); op[1] = f2bf(tile[j4 + 1][i]);
  op[2] = f2bf(tile[j4 + 2][i]); op[3] = f2bf(tile[j4 + 3][i]);
}

// V fp32 [b][n][512] -> bf16 head-blocked [b][h][n][64]
__global__ __launch_bounds__(256) void pack_vh(const float* __restrict__ Vs32,
                                               const float* __restrict__ Vc32,
                                               ushort_t* __restrict__ VsH,
                                               ushort_t* __restrict__ VcH) {
  const float* src = blockIdx.y ? Vc32 : Vs32;
  ushort_t* dst = blockIdx.y ? VcH : VsH;
  size_t idx = (size_t)blockIdx.x * 1024 + threadIdx.x * 4;
  float4 v = *(const float4*)(src + idx);
  int d512 = (int)(idx & 511);
  int n = (int)((idx >> 9) & 255);
  int b = (int)(idx >> 17);
  int h = d512 >> 6, d = d512 & 63;
  ushort_t* op = dst + (((size_t)(b * 8 + h) * NN + n) * DH + d);
  op[0] = f2bf(v.x); op[1] = f2bf(v.y); op[2] = f2bf(v.z); op[3] = f2bf(v.w);
}

// weights fp32 [col][k] -> bf16 packed [(k>>2)*C + col]*4 + (k&3)
struct PWItem { const float* in; ushort_t* out; int C; int K; };
struct PWArgs { PWItem m[10]; };
__global__ __launch_bounds__(256) void pack_w(PWArgs a) {
  PWItem it = a.m[blockIdx.y];
  int total = it.C * (it.K >> 2);
  int e = blockIdx.x * 256 + threadIdx.x;
  if (e >= total) return;
  int kd = it.K >> 2;
  int k4 = e % kd, col = e / kd;
  float4 v = *(const float4*)(it.in + (size_t)col * it.K + k4 * 4);
  ushort4 o;
  o.x = f2bf(v.x); o.y = f2bf(v.y); o.z = f2bf(v.z); o.w = f2bf(v.w);
  *((ushort4*)it.out + (size_t)k4 * it.C + col) = o;
}

__global__ __launch_bounds__(256) void init_x(const float* __restrict__ hv0,
                                              const float* __restrict__ pe,
                                              float* __restrict__ xcur,
                                              unsigned* __restrict__ flags) {
  int i = blockIdx.x * 256 + threadIdx.x;
  xcur[i] = hv0[i] + pe[i & (DD - 1)];
  if (i < 1024) flags[i] = 0u;
}

// ---------------------------------------------------------------------------
extern "C" void kernel_launch(void* const* d_in, const int* in_sizes, int n_in,
                              void* d_out, int out_size, void* d_ws, size_t ws_size,
                              hipStream_t stream) {
  const float* H_v_all = (const float*)d_in[0];
  const float* H_v0    = (const float*)d_in[1];
  const float* pe      = (const float*)d_in[2];
  const float* s_Wq = (const float*)d_in[3];
  const float* s_Wk = (const float*)d_in[4];
  const float* s_Wv = (const float*)d_in[5];
  const float* s_Wo = (const float*)d_in[6];
  const float* s_bq = (const float*)d_in[7];
  const float* s_bk = (const float*)d_in[8];
  const float* s_bv = (const float*)d_in[9];
  const float* s_bo = (const float*)d_in[10];
  const float* sa_Wq = (const float*)d_in[11];
  const float* sa_Wk = (const float*)d_in[12];
  const float* sa_Wv = (const float*)d_in[13];
  const float* sa_Wo = (const float*)d_in[14];
  const float* sa_bq = (const float*)d_in[15];
  const float* sa_bk = (const float*)d_in[16];
  const float* sa_bv = (const float*)d_in[17];
  const float* sa_bo = (const float*)d_in[18];
  const float* ca_Wq = (const float*)d_in[19];
  const float* ca_Wk = (const float*)d_in[20];
  const float* ca_Wv = (const float*)d_in[21];
  const float* ca_Wo = (const float*)d_in[22];
  const float* ca_bq = (const float*)d_in[23];
  const float* ca_bk = (const float*)d_in[24];
  const float* ca_bv = (const float*)d_in[25];
  const float* ca_bo = (const float*)d_in[26];
  const float* ln1w = (const float*)d_in[27];
  const float* ln1b = (const float*)d_in[28];
  const float* ln2w = (const float*)d_in[29];
  const float* ln2b = (const float*)d_in[30];
  const float* ln3w = (const float*)d_in[31];
  const float* ln3b = (const float*)d_in[32];
  const float* W1   = (const float*)d_in[33];
  const float* b1   = (const float*)d_in[34];
  const float* W2   = (const float*)d_in[35];
  const float* b2   = (const float*)d_in[36];
  const float* Wout = (const float*)d_in[37];
  const float* bout = (const float*)d_in[38];

  float* ws = (float*)d_ws;
  float* Ks32 = ws + OFF_KS32;
  float* Vs32 = ws + OFF_VS32;
  float* Kc32 = ws + OFF_KC32;
  float* Vc32 = ws + OFF_VC32;
  ushort_t* ub = (ushort_t*)(ws + OFF_BF);
  unsigned* flags = (unsigned*)(ws + OFF_FLG);

  // --- precompute -----------------------------------------------------------
  hipLaunchKernelGGL(gemm_kv, dim3(16, 64), dim3(256), 0, stream,
                     H_v_all, s_Wk, s_Wv, ca_Wk, ca_Wv,
                     s_bk, s_bv, ca_bk, ca_bv, Ks32, Vs32, Kc32, Vc32);

  hipLaunchKernelGGL(pack_kT, dim3(8, 16, 64), dim3(256), 0, stream,
                     Ks32, Kc32, ub + UOFF_KST, ub + UOFF_KCT);
  hipLaunchKernelGGL(pack_vh, dim3((unsigned)(SZ_KV / 1024), 2), dim3(256), 0,
                     stream, Vs32, Vc32, ub + UOFF_VSH, ub + UOFF_VCH);

  PWArgs pw;
  pw.m[0] = {sa_Wq, ub + UOFF_W8 + 0ull * DD * DD, DD, DD};
  pw.m[1] = {sa_Wk, ub + UOFF_W8 + 1ull * DD * DD, DD, DD};
  pw.m[2] = {sa_Wv, ub + UOFF_W8 + 2ull * DD * DD, DD, DD};
  pw.m[3] = {s_Wq,  ub + UOFF_W8 + 3ull * DD * DD, DD, DD};
  pw.m[4] = {sa_Wo, ub + UOFF_W8 + 4ull * DD * DD, DD, DD};
  pw.m[5] = {s_Wo,  ub + UOFF_W8 + 5ull * DD * DD, DD, DD};
  pw.m[6] = {ca_Wq, ub + UOFF_W8 + 6ull * DD * DD, DD, DD};
  pw.m[7] = {ca_Wo, ub + UOFF_W8 + 7ull * DD * DD, DD, DD};
  pw.m[8] = {W1, ub + UOFF_W1, DF, DD};   // C=2048 cols, K=512
  pw.m[9] = {W2, ub + UOFF_W2, DD, DF};   // C=512 cols, K=2048
  hipLaunchKernelGGL(pack_w, dim3(1024, 10), dim3(256), 0, stream, pw);

  hipLaunchKernelGGL(init_x, dim3(64), dim3(256), 0, stream,
                     H_v0, pe, ws + OFF_X, flags);

  // --- persistent decode ----------------------------------------------------
  Params P;
  P.pe = pe;
  P.sa_bq = sa_bq; P.sa_bk = sa_bk; P.sa_bv = sa_bv; P.s_bq = s_bq;
  P.sa_bo = sa_bo; P.s_bo = s_bo; P.ca_bq = ca_bq; P.ca_bo = ca_bo;
  P.ln1w = ln1w; P.ln1b = ln1b; P.ln2w = ln2w; P.ln2b = ln2b;
  P.ln3w = ln3w; P.ln3b = ln3b;
  P.b1 = b1; P.b2 = b2; P.Wout = Wout; P.bout = bout;
  P.w8 = ub + UOFF_W8; P.w1b = ub + UOFF_W1; P.w2b = ub + UOFF_W2;
  P.KsT = ub + UOFF_KST; P.KcT = ub + UOFF_KCT;
  P.VsH = ub + UOFF_VSH; P.VcH = ub + UOFF_VCH;
  P.KsaB = ub + UOFF_KSA; P.VsaB = ub + UOFF_VSA;
  P.xcur = ws + OFF_X;
  P.aSA = ws + OFF_ASA; P.aSP = ws + OFF_ASP; P.aCA = ws + OFF_ACA;
  P.u1 = ws + OFF_U1; P.y1 = ws + OFF_Y1; P.u2 = ws + OFF_U2;
  P.ctx = ws + OFF_CTX; P.u3 = ws + OFF_U3; P.hbuf = ws + OFF_H;
  P.out = (float*)d_out;
  P.flags = flags;
  P.rels = flags + 512;

  void* kargs[] = { (void*)&P };
  hipLaunchCooperativeKernel((void*)decode_persistent, dim3(NBLK), dim3(256),
                             kargs, 0, stream);
}

// Round 9
// 3693.408 us; speedup vs baseline: 2.2172x; 1.9096x over previous
//
#include <hip/hip_runtime.h>

// ---------------------------------------------------------------------------
// VehicleTrajectoryDecoder: B=32, N=256, D=512, H=8 (dh=64), T=60, DFF=2048.
// R9: R8 NaN'd from a divergent s_barrier (waves 4-7 paired with the wrong
// barrier -> block desync -> races on sAux). Fix: softmax restructured into
// full-block-synchronized stages (no barrier inside divergent code). All else
// identical to R8: 256 blocks x 512 threads (8 waves/CU, 2x MLP), 7 barriers,
// k-split gemvs with LDS partial reduce, bf16 weights/KV, sc1 activations.
// ---------------------------------------------------------------------------

#define NB 32
#define NN 256
#define DD 512
#define NH 8
#define DH 64
#define TT 60
#define DF 2048
#define NBLK 256
#define NTHR 512

typedef unsigned short ushort_t;

// ---- workspace layout ------------------------------------------------------
constexpr size_t SZ_KV  = (size_t)NB * NN * DD;   // 4194304
constexpr size_t SZ_ROW = (size_t)NB * DD;
constexpr size_t SZ_SAB = (size_t)NB * NH * TT * DH;
constexpr size_t OFF_KS32 = 0;
constexpr size_t OFF_VS32 = SZ_KV;
constexpr size_t OFF_KC32 = 2 * SZ_KV;
constexpr size_t OFF_VC32 = 3 * SZ_KV;
constexpr size_t OFF_X   = 0;
constexpr size_t OFF_ASA = OFF_X   + SZ_ROW;
constexpr size_t OFF_ASP = OFF_ASA + SZ_ROW;
constexpr size_t OFF_ACA = OFF_ASP + SZ_ROW;
constexpr size_t OFF_U1  = OFF_ACA + SZ_ROW;
constexpr size_t OFF_Y1  = OFF_U1  + SZ_ROW;
constexpr size_t OFF_U2  = OFF_Y1  + SZ_ROW;
constexpr size_t OFF_CTX = OFF_U2  + SZ_ROW;
constexpr size_t OFF_U3  = OFF_CTX + SZ_ROW;
constexpr size_t OFF_H   = OFF_U3  + SZ_ROW;
constexpr size_t OFF_BF   = 4 * SZ_KV;
constexpr size_t UOFF_KST = 0;
constexpr size_t UOFF_KCT = SZ_KV;
constexpr size_t UOFF_VSH = 2 * SZ_KV;
constexpr size_t UOFF_VCH = 3 * SZ_KV;
constexpr size_t UOFF_KSA = 4 * SZ_KV;
constexpr size_t UOFF_VSA = UOFF_KSA + SZ_SAB;
constexpr size_t UOFF_W8  = UOFF_VSA + SZ_SAB;
constexpr size_t UOFF_W1  = UOFF_W8 + 8ull * DD * DD;
constexpr size_t UOFF_W2  = UOFF_W1 + (size_t)DD * DF;
constexpr size_t UEND     = UOFF_W2 + (size_t)DF * DD;
constexpr size_t OFF_FLG  = OFF_BF + (UEND + 1) / 2;

// ---- helpers ----------------------------------------------------------------
__device__ __forceinline__ float ldg_a(const float* p) {
  return __hip_atomic_load(p, __ATOMIC_RELAXED, __HIP_MEMORY_SCOPE_AGENT);
}
__device__ __forceinline__ void stg_a(float* p, float v) {
  __hip_atomic_store(p, v, __ATOMIC_RELAXED, __HIP_MEMORY_SCOPE_AGENT);
}
__device__ __forceinline__ float bf2f(ushort_t u) {
  return __uint_as_float(((unsigned)u) << 16);
}
__device__ __forceinline__ ushort_t f2bf(float f) {
  unsigned u = __float_as_uint(f);
  return (ushort_t)((u + 0x7FFFu + ((u >> 16) & 1u)) >> 16);
}

// ---- params ----------------------------------------------------------------
struct Params {
  const float *pe;
  const float *sa_bq, *sa_bk, *sa_bv, *s_bq, *sa_bo, *s_bo, *ca_bq, *ca_bo;
  const float *ln1w, *ln1b, *ln2w, *ln2b, *ln3w, *ln3b;
  const float *b1, *b2, *Wout, *bout;
  const ushort_t *w8, *w1b, *w2b;
  const ushort_t *KsT, *KcT, *VsH, *VcH;
  ushort_t *KsaB, *VsaB;
  float *xcur, *aSA, *aSP, *aCA, *u1, *y1, *u2, *ctx, *u3, *hbuf;
  float *out;
  unsigned *flags, *rels;
};

// ---- grid barrier (proven R7 design; 512-thread aware) ----------------------
__device__ __forceinline__ void gsync(unsigned* flags, unsigned* rels,
                                      unsigned& round, int tid, int bid) {
  __builtin_amdgcn_s_waitcnt(0);
  __syncthreads();
  round++;
  if (bid == 0) {
    if (tid > 0 && tid < NBLK) {
      while (__hip_atomic_load(&flags[tid], __ATOMIC_RELAXED,
                               __HIP_MEMORY_SCOPE_AGENT) < round)
        __builtin_amdgcn_s_sleep(1);
    }
    __syncthreads();
    if (tid < NBLK)
      __hip_atomic_store(&rels[tid], round, __ATOMIC_RELAXED,
                         __HIP_MEMORY_SCOPE_AGENT);
  } else if (tid == 0) {
    __hip_atomic_store(&flags[bid], round, __ATOMIC_RELAXED,
                       __HIP_MEMORY_SCOPE_AGENT);
    while (__hip_atomic_load(&rels[bid], __ATOMIC_RELAXED,
                             __HIP_MEMORY_SCOPE_AGENT) < round)
      __builtin_amdgcn_s_sleep(1);
  }
  __syncthreads();
}

// ---- persistent decode (256 blocks x 512 threads) ---------------------------
__global__ __launch_bounds__(512) void decode_persistent(Params P) {
  __shared__ __align__(16) float sX[2048];    // 8KB multi-purpose
  __shared__ __align__(16) float sPart[512];  // 2KB k-split partials
  __shared__ float sAux[64];
  int tid = threadIdx.x;
  int bid = blockIdx.x;
  unsigned round = 0;

  for (int t = 0; t < TT; t++) {
    // ==== Phase 1: (b,h): proj q/k/v/qs head slices + self-attn + spatial ===
    {
      int b = bid >> 3, h = bid & 7;
      sX[tid] = ldg_a(P.xcur + (size_t)b * DD + tid);
      __syncthreads();
      // proj: wave w: matrix m=w>>1, k-half=w&1; lane c -> col h*64+c
      {
        int w = tid >> 6, c = tid & 63, m = w >> 1, half = w & 1;
        int col = h * DH + c;
        const ushort4* wp = (const ushort4*)(P.w8 + (size_t)m * DD * DD) + col;
        float acc = 0.f;
        #pragma unroll 8
        for (int kq = half * 64; kq < half * 64 + 64; kq++) {
          ushort4 wv = wp[(size_t)kq * DD];
          float4 xv = *(const float4*)(sX + kq * 4);
          acc += xv.x * bf2f(wv.x) + xv.y * bf2f(wv.y) +
                 xv.z * bf2f(wv.z) + xv.w * bf2f(wv.w);
        }
        sPart[tid] = acc;
      }
      __syncthreads();
      if (tid < 256) {  // combine halves + bias; stash in sX[512..768)
        int m = tid >> 6, c = tid & 63, col = h * DH + c;
        const float* bias = (m == 0) ? P.sa_bq : (m == 1) ? P.sa_bk
                          : (m == 2) ? P.sa_bv : P.s_bq;
        float val = sPart[(2 * m) * 64 + c] + sPart[(2 * m + 1) * 64 + c]
                    + bias[col];
        sX[512 + tid] = val;
        if (m == 1) P.KsaB[((size_t)bid * TT + t) * DH + c] = f2bf(val);
        if (m == 2) P.VsaB[((size_t)bid * TT + t) * DH + c] = f2bf(val);
      }
      __syncthreads();

      // ---- self-attn over L keys (head-private bf16 cache) ----
      int L = t + 1;
      float* sQ  = sX + 512;        // q_self [64]
      float* sQs = sX + 512 + 192;  // q_spatial [64]
      float* sPb = sX + 768;        // self probs [64]
      float* sB  = sX + 1024;       // partials [512]
      if (tid < 64) {
        float sc = -1e30f;
        if (tid < L) {
          const ushort_t* kp = P.KsaB + ((size_t)bid * TT + tid) * DH;
          float a = 0.f;
          #pragma unroll
          for (int i = 0; i < DH; i += 4) {
            ushort4 kv = *(const ushort4*)(kp + i);
            a += sQ[i] * bf2f(kv.x) + sQ[i + 1] * bf2f(kv.y) +
                 sQ[i + 2] * bf2f(kv.z) + sQ[i + 3] * bf2f(kv.w);
          }
          sc = a * 0.125f;
        }
        float mx = sc;
        #pragma unroll
        for (int s = 32; s >= 1; s >>= 1) mx = fmaxf(mx, __shfl_xor(mx, s));
        float e = (tid < L) ? __expf(sc - mx) : 0.f;
        float s2 = e;
        #pragma unroll
        for (int s = 32; s >= 1; s >>= 1) s2 += __shfl_xor(s2, s);
        sPb[tid] = e;
        if (tid == 0) sAux[12] = 1.f / s2;
      }
      __syncthreads();
      {  // PV: 8 key-groups x 64 d
        int g = tid >> 6, d = tid & 63;
        float a2 = 0.f;
        for (int j = g; j < L; j += 8)
          a2 += sPb[j] * bf2f(P.VsaB[((size_t)bid * TT + j) * DH + d]);
        sB[tid] = a2;
      }
      __syncthreads();
      if (tid < 64) {
        float o = 0.f;
        #pragma unroll
        for (int i = 0; i < 8; i++) o += sB[i * 64 + tid];
        stg_a(&P.aSA[(size_t)b * DD + h * DH + tid], o * sAux[12]);
      }
      __syncthreads();

      // ---- spatial attn over 256 keys (d-split scores, 8-way PV) ----
      {
        int n = tid & 255, dh2 = tid >> 8;  // d-half
        const ushort_t* kp = P.KsT + ((size_t)b * DD + h * DH) * NN + n;
        float a = 0.f;
        #pragma unroll 8
        for (int i = dh2 * 32; i < dh2 * 32 + 32; i++)
          a += sQs[i] * bf2f(kp[(size_t)i * NN]);
        sPart[tid] = a;
      }
      __syncthreads();
      float* sPr = sX + 1536;  // spatial probs [256]
      // softmax stage 1: raw score + wave max (full-block sync'd, no
      // divergent barrier — the R8 bug)
      if (tid < 256) {
        float sc = (sPart[tid] + sPart[256 + tid]) * 0.125f;
        sPr[tid] = sc;
        int w = tid >> 6, lane = tid & 63;
        float mx = sc;
        #pragma unroll
        for (int s = 32; s >= 1; s >>= 1) mx = fmaxf(mx, __shfl_xor(mx, s));
        if (lane == 0) sAux[w] = mx;
      }
      __syncthreads();
      // softmax stage 2: exp + wave sum
      if (tid < 256) {
        int w = tid >> 6, lane = tid & 63;
        float mx = fmaxf(fmaxf(sAux[0], sAux[1]), fmaxf(sAux[2], sAux[3]));
        float e = __expf(sPr[tid] - mx);
        sPr[tid] = e;
        float s2 = e;
        #pragma unroll
        for (int s = 32; s >= 1; s >>= 1) s2 += __shfl_xor(s2, s);
        if (lane == 0) sAux[4 + w] = s2;
      }
      __syncthreads();
      {
        int g = tid >> 6, d = tid & 63;
        float inv = 1.f / (sAux[4] + sAux[5] + sAux[6] + sAux[7]);
        const ushort_t* vp = P.VsH + ((size_t)bid * NN + g * 32) * DH + d;
        float acc = 0.f;
        #pragma unroll 4
        for (int n = 0; n < 32; n++) acc += sPr[g * 32 + n] * bf2f(vp[(size_t)n * DH]);
        sB[tid] = acc * inv;
      }
      __syncthreads();
      if (tid < 64) {
        float o = 0.f;
        #pragma unroll
        for (int i = 0; i < 8; i++) o += sB[i * 64 + tid];
        stg_a(&P.aSP[(size_t)b * DD + h * DH + tid], o);
      }
    }
    gsync(P.flags, P.rels, round, tid, bid);

    // ==== Phase 2: u1 = aSA@saWo + sa_bo + x ; ctx = aSP@sWo + s_bo =========
    {
      int s = bid & 7, mz = (bid >> 3) & 1, bg = bid >> 4;  // 2 rows/block
      const float* src = (mz ? P.aSP : P.aSA) + (size_t)bg * 2 * DD;
      #pragma unroll
      for (int q = 0; q < 2; q++) sX[q * 512 + tid] = ldg_a(src + q * 512 + tid);
      __syncthreads();
      {
        int c = tid & 63, r = (tid >> 6) & 1, kh = tid >> 7, col = s * DH + c;
        const float* xr = sX + r * DD;
        const ushort4* wp = (const ushort4*)(P.w8 + (size_t)(4 + mz) * DD * DD) + col;
        float acc = 0.f;
        #pragma unroll 8
        for (int kq = kh * 32; kq < kh * 32 + 32; kq++) {
          ushort4 wv = wp[(size_t)kq * DD];
          float4 xv = *(const float4*)(xr + kq * 4);
          acc += xv.x * bf2f(wv.x) + xv.y * bf2f(wv.y) +
                 xv.z * bf2f(wv.z) + xv.w * bf2f(wv.w);
        }
        sPart[tid] = acc;
      }
      __syncthreads();
      if (tid < 128) {
        int r = tid >> 6, c = tid & 63, col = s * DH + c, b = bg * 2 + r;
        float acc = sPart[tid] + sPart[128 + tid] + sPart[256 + tid] + sPart[384 + tid];
        if (mz == 0)
          stg_a(&P.u1[(size_t)b * DD + col],
                acc + P.sa_bo[col] + ldg_a(&P.xcur[(size_t)b * DD + col]));
        else
          stg_a(&P.ctx[(size_t)b * DD + col], acc + P.s_bo[col]);
      }
    }
    gsync(P.flags, P.rels, round, tid, bid);

    // ==== Phase 3: LN1(u1) ; y1(h==0) ; qc head ; cross-attn ================
    {
      int b = bid >> 3, h = bid & 7;
      float v = ldg_a(P.u1 + (size_t)b * DD + tid);
      {  // LN over 512 with 8 waves
        int w = tid >> 6, lane = tid & 63;
        float s = v, q2 = v * v;
        #pragma unroll
        for (int m = 32; m >= 1; m >>= 1) { s += __shfl_xor(s, m); q2 += __shfl_xor(q2, m); }
        if (lane == 0) { sAux[w] = s; sAux[8 + w] = q2; }
      }
      __syncthreads();
      {
        float ss = 0.f, qq = 0.f;
        #pragma unroll
        for (int i = 0; i < 8; i++) { ss += sAux[i]; qq += sAux[8 + i]; }
        float mean = ss * (1.f / 512.f);
        float inv = rsqrtf(qq * (1.f / 512.f) - mean * mean + 1e-5f);
        float y = (v - mean) * inv * P.ln1w[tid] + P.ln1b[tid];
        sX[tid] = y;
        if (h == 0) stg_a(&P.y1[(size_t)b * DD + tid], y);
      }
      __syncthreads();
      {  // qc: 8 k-chunks of 64
        int c = tid & 63, w = tid >> 6, col = h * DH + c;
        const ushort4* wp = (const ushort4*)(P.w8 + 6ull * DD * DD) + col;
        float acc = 0.f;
        #pragma unroll 8
        for (int kq = w * 16; kq < w * 16 + 16; kq++) {
          ushort4 wv = wp[(size_t)kq * DD];
          float4 xv = *(const float4*)(sX + kq * 4);
          acc += xv.x * bf2f(wv.x) + xv.y * bf2f(wv.y) +
                 xv.z * bf2f(wv.z) + xv.w * bf2f(wv.w);
        }
        sPart[tid] = acc;
      }
      __syncthreads();
      float* sQc = sX + 512;
      if (tid < 64) {
        float acc = 0.f;
        #pragma unroll
        for (int i = 0; i < 8; i++) acc += sPart[i * 64 + tid];
        sQc[tid] = acc + P.ca_bq[h * DH + tid];
      }
      __syncthreads();
      // cross-attn scores (d-split)
      {
        int n = tid & 255, dh2 = tid >> 8;
        const ushort_t* kp = P.KcT + ((size_t)b * DD + h * DH) * NN + n;
        float a = 0.f;
        #pragma unroll 8
        for (int i = dh2 * 32; i < dh2 * 32 + 32; i++)
          a += sQc[i] * bf2f(kp[(size_t)i * NN]);
        sPart[tid] = a;
      }
      __syncthreads();
      float* sPr = sX + 1536;
      if (tid < 256) {  // softmax stage 1 (full-block sync'd)
        float sc = (sPart[tid] + sPart[256 + tid]) * 0.125f;
        sPr[tid] = sc;
        int w = tid >> 6, lane = tid & 63;
        float mx = sc;
        #pragma unroll
        for (int s = 32; s >= 1; s >>= 1) mx = fmaxf(mx, __shfl_xor(mx, s));
        if (lane == 0) sAux[w] = mx;
      }
      __syncthreads();
      if (tid < 256) {  // softmax stage 2
        int w = tid >> 6, lane = tid & 63;
        float mx = fmaxf(fmaxf(sAux[0], sAux[1]), fmaxf(sAux[2], sAux[3]));
        float e = __expf(sPr[tid] - mx);
        sPr[tid] = e;
        float s2 = e;
        #pragma unroll
        for (int s = 32; s >= 1; s >>= 1) s2 += __shfl_xor(s2, s);
        if (lane == 0) sAux[4 + w] = s2;
      }
      __syncthreads();
      float* sB = sX + 1024;
      {
        int g = tid >> 6, d = tid & 63;
        float inv = 1.f / (sAux[4] + sAux[5] + sAux[6] + sAux[7]);
        const ushort_t* vp = P.VcH + ((size_t)bid * NN + g * 32) * DH + d;
        float acc = 0.f;
        #pragma unroll 4
        for (int n = 0; n < 32; n++) acc += sPr[g * 32 + n] * bf2f(vp[(size_t)n * DH]);
        sB[tid] = acc * inv;
      }
      __syncthreads();
      if (tid < 64) {
        float o = 0.f;
        #pragma unroll
        for (int i = 0; i < 8; i++) o += sB[i * 64 + tid];
        stg_a(&P.aCA[(size_t)b * DD + h * DH + tid], o);
      }
    }
    gsync(P.flags, P.rels, round, tid, bid);

    // ==== Phase 4: u2 = aCA@caWo + ca_bo + y1 (128 blocks) ==================
    if (bid < 128) {
      int s = bid & 7, bg = bid >> 3;  // 2 rows
      const float* src = P.aCA + (size_t)bg * 2 * DD;
      #pragma unroll
      for (int q = 0; q < 2; q++) sX[q * 512 + tid] = ldg_a(src + q * 512 + tid);
      __syncthreads();
      {
        int c = tid & 63, r = (tid >> 6) & 1, kh = tid >> 7, col = s * DH + c;
        const float* xr = sX + r * DD;
        const ushort4* wp = (const ushort4*)(P.w8 + 7ull * DD * DD) + col;
        float acc = 0.f;
        #pragma unroll 8
        for (int kq = kh * 32; kq < kh * 32 + 32; kq++) {
          ushort4 wv = wp[(size_t)kq * DD];
          float4 xv = *(const float4*)(xr + kq * 4);
          acc += xv.x * bf2f(wv.x) + xv.y * bf2f(wv.y) +
                 xv.z * bf2f(wv.z) + xv.w * bf2f(wv.w);
        }
        sPart[tid] = acc;
      }
      __syncthreads();
      if (tid < 128) {
        int r = tid >> 6, c = tid & 63, col = s * DH + c, b = bg * 2 + r;
        float acc = sPart[tid] + sPart[128 + tid] + sPart[256 + tid] + sPart[384 + tid];
        stg_a(&P.u2[(size_t)b * DD + col],
              acc + P.ca_bo[col] + ldg_a(&P.y1[(size_t)b * DD + col]));
      }
    }
    gsync(P.flags, P.rels, round, tid, bid);

    // ==== Phase 5: LN2(u2)=z ; u3=z+b2 ; hbuf=relu(z@W1+b1) =================
    {
      int c0 = (bid & 31) * 64, bg = bid >> 5;  // 4 rows, 64 cols of 2048
      const float* src = P.u2 + (size_t)bg * 4 * DD;
      #pragma unroll
      for (int q = 0; q < 4; q++) sX[q * 512 + tid] = ldg_a(src + q * 512 + tid);
      __syncthreads();
      {  // LN of 4 rows; wave w: row w>>1, half-row w&1
        int w = tid >> 6, lane = tid & 63, r = w >> 1, hr = w & 1;
        float s = 0.f, q2 = 0.f;
        #pragma unroll
        for (int i = 0; i < 4; i++) {
          float v = sX[r * DD + hr * 256 + lane + i * 64];
          s += v; q2 += v * v;
        }
        #pragma unroll
        for (int m = 32; m >= 1; m >>= 1) { s += __shfl_xor(s, m); q2 += __shfl_xor(q2, m); }
        if (lane == 0) { sAux[w] = s; sAux[8 + w] = q2; }
      }
      __syncthreads();
      #pragma unroll
      for (int i = 0; i < 4; i++) {
        int idx = i * 512 + tid, r = idx >> 9, col = idx & 511;
        float mean = (sAux[2 * r] + sAux[2 * r + 1]) * (1.f / 512.f);
        float inv = rsqrtf((sAux[8 + 2 * r] + sAux[8 + 2 * r + 1]) * (1.f / 512.f)
                           - mean * mean + 1e-5f);
        sX[idx] = (sX[idx] - mean) * inv * P.ln2w[col] + P.ln2b[col];
      }
      __syncthreads();
      if ((bid & 31) == 0) {
        #pragma unroll
        for (int i = 0; i < 4; i++) {
          int idx = i * 512 + tid, r = idx >> 9, col = idx & 511;
          stg_a(&P.u3[(size_t)(bg * 4 + r) * DD + col], sX[idx] + P.b2[col]);
        }
      }
      {
        int c = tid & 63, r = (tid >> 6) & 3, kh = tid >> 8, col = c0 + c;
        const float* xr = sX + r * DD;
        const ushort4* wp = (const ushort4*)P.w1b + col;
        float acc = 0.f;
        #pragma unroll 8
        for (int kq = kh * 64; kq < kh * 64 + 64; kq++) {
          ushort4 wv = wp[(size_t)kq * DF];
          float4 xv = *(const float4*)(xr + kq * 4);
          acc += xv.x * bf2f(wv.x) + xv.y * bf2f(wv.y) +
                 xv.z * bf2f(wv.z) + xv.w * bf2f(wv.w);
        }
        sPart[tid] = acc;
      }
      __syncthreads();
      if (tid < 256) {
        int r = tid >> 6, c = tid & 63, col = c0 + c, b = bg * 4 + r;
        float acc = sPart[tid] + sPart[256 + tid];
        stg_a(&P.hbuf[(size_t)b * DF + col], fmaxf(acc + P.b1[col], 0.f));
      }
    }
    gsync(P.flags, P.rels, round, tid, bid);

    // ==== Phase 6: u3 += hbuf@W2 (split-k x4, atomics) ======================
    {
      int s = bid & 7, ks = (bid >> 3) & 3, bg = bid >> 5;
      int k0 = ks * 512;
      #pragma unroll
      for (int q = 0; q < 4; q++) {
        int f = q * 512 + tid, r = f >> 9, cc = f & 511;
        sX[f] = ldg_a(&P.hbuf[(size_t)(bg * 4 + r) * DF + k0 + cc]);
      }
      __syncthreads();
      {
        int c = tid & 63, r = (tid >> 6) & 3, kh = tid >> 8, col = s * DH + c;
        const float* xr = sX + r * DD;
        const ushort4* wp = (const ushort4*)P.w2b + (size_t)(k0 >> 2) * DD + col;
        float acc = 0.f;
        #pragma unroll 8
        for (int kq = kh * 64; kq < kh * 64 + 64; kq++) {
          ushort4 wv = wp[(size_t)kq * DD];
          float4 xv = *(const float4*)(xr + kq * 4);
          acc += xv.x * bf2f(wv.x) + xv.y * bf2f(wv.y) +
                 xv.z * bf2f(wv.z) + xv.w * bf2f(wv.w);
        }
        sPart[tid] = acc;
      }
      __syncthreads();
      if (tid < 256) {
        int r = tid >> 6, c = tid & 63, col = s * DH + c, b = bg * 4 + r;
        atomicAdd(&P.u3[(size_t)b * DD + col], sPart[tid] + sPart[256 + tid]);
      }
    }
    gsync(P.flags, P.rels, round, tid, bid);

    // ==== Phase 7: nxt = LN3(u3)+ctx ; out ; xcur = nxt + pe[t+1] ===========
    if (bid < NB) {
      int b = bid;
      float u = ldg_a(&P.u3[(size_t)b * DD + tid]);
      {
        int w = tid >> 6, lane = tid & 63;
        float s = u, q2 = u * u;
        #pragma unroll
        for (int m = 32; m >= 1; m >>= 1) { s += __shfl_xor(s, m); q2 += __shfl_xor(q2, m); }
        if (lane == 0) { sAux[w] = s; sAux[8 + w] = q2; }
      }
      __syncthreads();
      float ss = 0.f, qq = 0.f;
      #pragma unroll
      for (int i = 0; i < 8; i++) { ss += sAux[i]; qq += sAux[8 + i]; }
      float mean = ss * (1.f / 512.f);
      float inv = rsqrtf(qq * (1.f / 512.f) - mean * mean + 1e-5f);
      float nxt = (u - mean) * inv * P.ln3w[tid] + P.ln3b[tid] +
                  ldg_a(&P.ctx[(size_t)b * DD + tid]);
      sX[tid] = nxt;
      float p = (t < TT - 1) ? P.pe[(size_t)(t + 1) * DD + tid] : 0.f;
      stg_a(&P.xcur[(size_t)b * DD + tid], nxt + p);
      __syncthreads();
      {
        int c = tid >> 8, l = tid & 255;
        float a = sX[l] * P.Wout[(size_t)c * DD + l] +
                  sX[l + 256] * P.Wout[(size_t)c * DD + l + 256];
        #pragma unroll
        for (int m = 32; m >= 1; m >>= 1) a += __shfl_xor(a, m);
        if ((tid & 63) == 0) sAux[16 + (tid >> 6)] = a;
      }
      __syncthreads();
      if (tid == 0)
        P.out[((size_t)b * TT + t) * 2 + 0] =
            sAux[16] + sAux[17] + sAux[18] + sAux[19] + P.bout[0];
      if (tid == 256)
        P.out[((size_t)b * TT + t) * 2 + 1] =
            sAux[20] + sAux[21] + sAux[22] + sAux[23] + P.bout[1];
    }
    gsync(P.flags, P.rels, round, tid, bid);
  }
}

// ---- precompute kernels (unchanged from R7) ---------------------------------
__global__ __launch_bounds__(256) void gemm_kv(
    const float* __restrict__ A,
    const float* __restrict__ W0, const float* __restrict__ W1_,
    const float* __restrict__ W2_, const float* __restrict__ W3_,
    const float* __restrict__ b0, const float* __restrict__ b1_,
    const float* __restrict__ b2_, const float* __restrict__ b3_,
    float* __restrict__ O0, float* __restrict__ O1,
    float* __restrict__ O2, float* __restrict__ O3) {
  __shared__ __align__(16) float As[8][128];
  __shared__ __align__(16) float Bs[8][128];
  int tid = threadIdx.x;
  int bx = blockIdx.x, by = blockIdx.y;
  int mm = bx >> 2;
  int col0 = (bx & 3) * 128;
  const float* W = mm == 0 ? W0 : mm == 1 ? W1_ : mm == 2 ? W2_ : W3_;
  const float* bias = mm == 0 ? b0 : mm == 1 ? b1_ : mm == 2 ? b2_ : b3_;
  float* O = mm == 0 ? O0 : mm == 1 ? O1 : mm == 2 ? O2 : O3;
  int tx = tid & 15, ty = tid >> 4;
  int m0 = by * 128;
  int lr = tid >> 1, lk = (tid & 1) * 4;
  const float* Ap = A + (size_t)(m0 + lr) * DD + lk;
  const float* Wp = W + (size_t)(col0 + lr) * DD + lk;
  float c[8][8] = {};
  for (int k0 = 0; k0 < DD; k0 += 8) {
    float4 av = *(const float4*)(Ap + k0);
    float4 wv = *(const float4*)(Wp + k0);
    __syncthreads();
    As[lk + 0][lr] = av.x; As[lk + 1][lr] = av.y; As[lk + 2][lr] = av.z; As[lk + 3][lr] = av.w;
    Bs[lk + 0][lr] = wv.x; Bs[lk + 1][lr] = wv.y; Bs[lk + 2][lr] = wv.z; Bs[lk + 3][lr] = wv.w;
    __syncthreads();
    #pragma unroll
    for (int k = 0; k < 8; k++) {
      float a[8], bb[8];
      *(float4*)&a[0] = *(const float4*)&As[k][ty * 8];
      *(float4*)&a[4] = *(const float4*)&As[k][ty * 8 + 4];
      *(float4*)&bb[0] = *(const float4*)&Bs[k][tx * 8];
      *(float4*)&bb[4] = *(const float4*)&Bs[k][tx * 8 + 4];
      #pragma unroll
      for (int i = 0; i < 8; i++)
        #pragma unroll
        for (int j = 0; j < 8; j++) c[i][j] += a[i] * bb[j];
    }
  }
  const float* bp = bias + col0 + tx * 8;
  for (int i = 0; i < 8; i++) {
    int row = m0 + ty * 8 + i;
    float* op = O + (size_t)row * DD + col0 + tx * 8;
    #pragma unroll
    for (int jq = 0; jq < 8; jq += 4) {
      float4 v;
      v.x = c[i][jq + 0] + bp[jq + 0];
      v.y = c[i][jq + 1] + bp[jq + 1];
      v.z = c[i][jq + 2] + bp[jq + 2];
      v.w = c[i][jq + 3] + bp[jq + 3];
      *(float4*)(op + jq) = v;
    }
  }
}

__global__ __launch_bounds__(256) void pack_kT(const float* __restrict__ Ks32,
                                               const float* __restrict__ Kc32,
                                               ushort_t* __restrict__ KsT,
                                               ushort_t* __restrict__ KcT) {
  int z = blockIdx.z;
  int b = z >> 1;
  const float* in = ((z & 1) ? Kc32 : Ks32) + (size_t)b * NN * DD;
  ushort_t* out = ((z & 1) ? KcT : KsT) + (size_t)b * NN * DD;
  int r0 = blockIdx.x * 32, c0 = blockIdx.y * 32;
  __shared__ float tile[32][33];
  int tid = threadIdx.x;
  int i = tid >> 3, j4 = (tid & 7) * 4;
  float4 v = *(const float4*)(in + (size_t)(r0 + i) * DD + c0 + j4);
  tile[i][j4] = v.x; tile[i][j4 + 1] = v.y; tile[i][j4 + 2] = v.z; tile[i][j4 + 3] = v.w;
  __syncthreads();
  ushort_t* op = out + (size_t)(c0 + i) * NN + r0 + j4;
  op[0] = f2bf(tile[j4][i]); op[1] = f2bf(tile[j4 + 1][i]);
  op[2] = f2bf(tile[j4 + 2][i]); op[3] = f2bf(tile[j4 + 3][i]);
}

__global__ __launch_bounds__(256) void pack_vh(const float* __restrict__ Vs32,
                                               const float* __restrict__ Vc32,
                                               ushort_t* __restrict__ VsH,
                                               ushort_t* __restrict__ VcH) {
  const float* src = blockIdx.y ? Vc32 : Vs32;
  ushort_t* dst = blockIdx.y ? VcH : VsH;
  size_t idx = (size_t)blockIdx.x * 1024 + threadIdx.x * 4;
  float4 v = *(const float4*)(src + idx);
  int d512 = (int)(idx & 511);
  int n = (int)((idx >> 9) & 255);
  int b = (int)(idx >> 17);
  int h = d512 >> 6, d = d512 & 63;
  ushort_t* op = dst + (((size_t)(b * 8 + h) * NN + n) * DH + d);
  op[0] = f2bf(v.x); op[1] = f2bf(v.y); op[2] = f2bf(v.z); op[3] = f2bf(v.w);
}

struct PWItem { const float* in; ushort_t* out; int C; int K; };
struct PWArgs { PWItem m[10]; };
__global__ __launch_bounds__(256) void pack_w(PWArgs a) {
  PWItem it = a.m[blockIdx.y];
  int total = it.C * (it.K >> 2);
  int e = blockIdx.x * 256 + threadIdx.x;
  if (e >= total) return;
  int kd = it.K >> 2;
  int k4 = e % kd, col = e / kd;
  float4 v = *(const float4*)(it.in + (size_t)col * it.K + k4 * 4);
  ushort4 o;
  o.x = f2bf(v.x); o.y = f2bf(v.y); o.z = f2bf(v.z); o.w = f2bf(v.w);
  *((ushort4*)it.out + (size_t)k4 * it.C + col) = o;
}

__global__ __launch_bounds__(256) void init_x(const float* __restrict__ hv0,
                                              const float* __restrict__ pe,
                                              float* __restrict__ xcur,
                                              unsigned* __restrict__ flags) {
  int i = blockIdx.x * 256 + threadIdx.x;
  xcur[i] = hv0[i] + pe[i & (DD - 1)];
  if (i < 1024) flags[i] = 0u;
}

// ---------------------------------------------------------------------------
extern "C" void kernel_launch(void* const* d_in, const int* in_sizes, int n_in,
                              void* d_out, int out_size, void* d_ws, size_t ws_size,
                              hipStream_t stream) {
  const float* H_v_all = (const float*)d_in[0];
  const float* H_v0    = (const float*)d_in[1];
  const float* pe      = (const float*)d_in[2];
  const float* s_Wq = (const float*)d_in[3];
  const float* s_Wk = (const float*)d_in[4];
  const float* s_Wv = (const float*)d_in[5];
  const float* s_Wo = (const float*)d_in[6];
  const float* s_bq = (const float*)d_in[7];
  const float* s_bk = (const float*)d_in[8];
  const float* s_bv = (const float*)d_in[9];
  const float* s_bo = (const float*)d_in[10];
  const float* sa_Wq = (const float*)d_in[11];
  const float* sa_Wk = (const float*)d_in[12];
  const float* sa_Wv = (const float*)d_in[13];
  const float* sa_Wo = (const float*)d_in[14];
  const float* sa_bq = (const float*)d_in[15];
  const float* sa_bk = (const float*)d_in[16];
  const float* sa_bv = (const float*)d_in[17];
  const float* sa_bo = (const float*)d_in[18];
  const float* ca_Wq = (const float*)d_in[19];
  const float* ca_Wk = (const float*)d_in[20];
  const float* ca_Wv = (const float*)d_in[21];
  const float* ca_Wo = (const float*)d_in[22];
  const float* ca_bq = (const float*)d_in[23];
  const float* ca_bk = (const float*)d_in[24];
  const float* ca_bv = (const float*)d_in[25];
  const float* ca_bo = (const float*)d_in[26];
  const float* ln1w = (const float*)d_in[27];
  const float* ln1b = (const float*)d_in[28];
  const float* ln2w = (const float*)d_in[29];
  const float* ln2b = (const float*)d_in[30];
  const float* ln3w = (const float*)d_in[31];
  const float* ln3b = (const float*)d_in[32];
  const float* W1   = (const float*)d_in[33];
  const float* b1   = (const float*)d_in[34];
  const float* W2   = (const float*)d_in[35];
  const float* b2   = (const float*)d_in[36];
  const float* Wout = (const float*)d_in[37];
  const float* bout = (const float*)d_in[38];

  float* ws = (float*)d_ws;
  float* Ks32 = ws + OFF_KS32;
  float* Vs32 = ws + OFF_VS32;
  float* Kc32 = ws + OFF_KC32;
  float* Vc32 = ws + OFF_VC32;
  ushort_t* ub = (ushort_t*)(ws + OFF_BF);
  unsigned* flags = (unsigned*)(ws + OFF_FLG);

  hipLaunchKernelGGL(gemm_kv, dim3(16, 64), dim3(256), 0, stream,
                     H_v_all, s_Wk, s_Wv, ca_Wk, ca_Wv,
                     s_bk, s_bv, ca_bk, ca_bv, Ks32, Vs32, Kc32, Vc32);

  hipLaunchKernelGGL(pack_kT, dim3(8, 16, 64), dim3(256), 0, stream,
                     Ks32, Kc32, ub + UOFF_KST, ub + UOFF_KCT);
  hipLaunchKernelGGL(pack_vh, dim3((unsigned)(SZ_KV / 1024), 2), dim3(256), 0,
                     stream, Vs32, Vc32, ub + UOFF_VSH, ub + UOFF_VCH);

  PWArgs pw;
  pw.m[0] = {sa_Wq, ub + UOFF_W8 + 0ull * DD * DD, DD, DD};
  pw.m[1] = {sa_Wk, ub + UOFF_W8 + 1ull * DD * DD, DD, DD};
  pw.m[2] = {sa_Wv, ub + UOFF_W8 + 2ull * DD * DD, DD, DD};
  pw.m[3] = {s_Wq,  ub + UOFF_W8 + 3ull * DD * DD, DD, DD};
  pw.m[4] = {sa_Wo, ub + UOFF_W8 + 4ull * DD * DD, DD, DD};
  pw.m[5] = {s_Wo,  ub + UOFF_W8 + 5ull * DD * DD, DD, DD};
  pw.m[6] = {ca_Wq, ub + UOFF_W8 + 6ull * DD * DD, DD, DD};
  pw.m[7] = {ca_Wo, ub + UOFF_W8 + 7ull * DD * DD, DD, DD};
  pw.m[8] = {W1, ub + UOFF_W1, DF, DD};
  pw.m[9] = {W2, ub + UOFF_W2, DD, DF};
  hipLaunchKernelGGL(pack_w, dim3(1024, 10), dim3(256), 0, stream, pw);

  hipLaunchKernelGGL(init_x, dim3(64), dim3(256), 0, stream,
                     H_v0, pe, ws + OFF_X, flags);

  Params P;
  P.pe = pe;
  P.sa_bq = sa_bq; P.sa_bk = sa_bk; P.sa_bv = sa_bv; P.s_bq = s_bq;
  P.sa_bo = sa_bo; P.s_bo = s_bo; P.ca_bq = ca_bq; P.ca_bo = ca_bo;
  P.ln1w = ln1w; P.ln1b = ln1b; P.ln2w = ln2w; P.ln2b = ln2b;
  P.ln3w = ln3w; P.ln3b = ln3b;
  P.b1 = b1; P.b2 = b2; P.Wout = Wout; P.bout = bout;
  P.w8 = ub + UOFF_W8; P.w1b = ub + UOFF_W1; P.w2b = ub + UOFF_W2;
  P.KsT = ub + UOFF_KST; P.KcT = ub + UOFF_KCT;
  P.VsH = ub + UOFF_VSH; P.VcH = ub + UOFF_VCH;
  P.KsaB = ub + UOFF_KSA; P.VsaB = ub + UOFF_VSA;
  P.xcur = ws + OFF_X;
  P.aSA = ws + OFF_ASA; P.aSP = ws + OFF_ASP; P.aCA = ws + OFF_ACA;
  P.u1 = ws + OFF_U1; P.y1 = ws + OFF_Y1; P.u2 = ws + OFF_U2;
  P.ctx = ws + OFF_CTX; P.u3 = ws + OFF_U3; P.hbuf = ws + OFF_H;
  P.out = (float*)d_out;
  P.flags = flags;
  P.rels = flags + 512;

  void* kargs[] = { (void*)&P };
  hipLaunchCooperativeKernel((void*)decode_persistent, dim3(NBLK), dim3(NTHR),
                             kargs, 0, stream);
}